// Round 1
// baseline (5062.524 us; speedup 1.0000x reference)
//
#include <hip/hip_runtime.h>

#define H_N   100000
#define E_N   200000
#define NI_N  1000000
#define D_H   128
#define D_E   64
#define D_IN  192      // D_H + D_E
#define D_OUT 128
#define LN_EPS 1e-5f

// ---------------------------------------------------------------------------
// K1: node -> edge scatter-add. 64 lanes per incidence, 2 floats per lane.
// ---------------------------------------------------------------------------
__global__ __launch_bounds__(256) void k_scatter_n2e(
    const float* __restrict__ x_h, const int* __restrict__ fg,
    const int* __restrict__ res, float* __restrict__ edge_acc,
    float* __restrict__ cnt_e) {
  int inc  = blockIdx.x * 4 + (threadIdx.x >> 6);   // wave-uniform
  int lane = threadIdx.x & 63;
  int f = fg[inc];
  int r = res[inc];
  float2 v = ((const float2*)(x_h + (size_t)f * D_H))[lane];
  float* dst = edge_acc + (size_t)r * D_H + lane * 2;
  atomicAdd(dst, v.x);
  atomicAdd(dst + 1, v.y);
  if (lane == 0) atomicAdd(cnt_e + r, 1.0f);
}

// ---------------------------------------------------------------------------
// K2: edge MLP: relu(W1 * [mean||attr] + b1) -> W2*h + b2, 4 edges per block.
// Writes edge_msg in place over edge_acc (reads complete before first sync).
// ---------------------------------------------------------------------------
__global__ __launch_bounds__(128) void k_edge_mlp(
    const float* __restrict__ attr,
    const float* __restrict__ We1, const float* __restrict__ be1,
    const float* __restrict__ We2, const float* __restrict__ be2,
    float* __restrict__ edge_buf, const float* __restrict__ cnt_e) {
  __shared__ float s_in[4][D_IN];
  __shared__ float s_h1[4][D_OUT];
  __shared__ float s_inv[4];
  const int tid = threadIdx.x;
  const int e0  = blockIdx.x * 4;

  if (tid < 4) s_inv[tid] = 1.0f / fmaxf(cnt_e[e0 + tid], 1.0f);
  __syncthreads();

  for (int idx = tid; idx < 4 * D_IN; idx += 128) {
    int j = idx / D_IN;
    int k = idx - j * D_IN;
    int e = e0 + j;
    s_in[j][k] = (k < D_H) ? edge_buf[(size_t)e * D_H + k] * s_inv[j]
                           : attr[(size_t)e * D_E + (k - D_H)];
  }
  __syncthreads();

  {
    float b = be1[tid];
    float acc[4] = {b, b, b, b};
    const float* w = We1 + (size_t)tid * D_IN;
#pragma unroll 4
    for (int k = 0; k < D_IN; ++k) {
      float wv = w[k];
#pragma unroll
      for (int j = 0; j < 4; ++j) acc[j] += wv * s_in[j][k];
    }
#pragma unroll
    for (int j = 0; j < 4; ++j) s_h1[j][tid] = fmaxf(acc[j], 0.0f);
  }
  __syncthreads();

  {
    float b = be2[tid];
    float acc[4] = {b, b, b, b};
    const float* w = We2 + (size_t)tid * D_OUT;
#pragma unroll 4
    for (int k = 0; k < D_OUT; ++k) {
      float wv = w[k];
#pragma unroll
      for (int j = 0; j < 4; ++j) acc[j] += wv * s_h1[j][k];
    }
#pragma unroll
    for (int j = 0; j < 4; ++j)
      edge_buf[(size_t)(e0 + j) * D_OUT + tid] = acc[j];
  }
}

// ---------------------------------------------------------------------------
// K3: edge -> node scatter-add of edge messages.
// ---------------------------------------------------------------------------
__global__ __launch_bounds__(256) void k_scatter_e2n(
    const float* __restrict__ edge_buf, const int* __restrict__ fg,
    const int* __restrict__ res, float* __restrict__ node_acc,
    float* __restrict__ cnt_h) {
  int inc  = blockIdx.x * 4 + (threadIdx.x >> 6);
  int lane = threadIdx.x & 63;
  int f = fg[inc];
  int r = res[inc];
  float2 v = ((const float2*)(edge_buf + (size_t)r * D_OUT))[lane];
  float* dst = node_acc + (size_t)f * D_OUT + lane * 2;
  atomicAdd(dst, v.x);
  atomicAdd(dst + 1, v.y);
  if (lane == 0) atomicAdd(cnt_h + f, 1.0f);
}

// ---------------------------------------------------------------------------
// K4: node MLP + residual projection + relu + LayerNorm. 4 nodes per block.
// ---------------------------------------------------------------------------
__global__ __launch_bounds__(128) void k_node_mlp_ln(
    const float* __restrict__ x_h, const float* __restrict__ node_acc,
    const float* __restrict__ cnt_h,
    const float* __restrict__ Wp,  const float* __restrict__ bp,
    const float* __restrict__ Wn1, const float* __restrict__ bn1,
    const float* __restrict__ Wn2, const float* __restrict__ bn2,
    const float* __restrict__ gamma, const float* __restrict__ beta,
    float* __restrict__ out) {
  __shared__ float s_msg[4][D_OUT];
  __shared__ float s_x[4][D_H];
  __shared__ float s_t[4][D_OUT];
  __shared__ float s_z[4][D_OUT];
  __shared__ float s_stat[4][2];
  __shared__ float s_inv[4];
  const int tid = threadIdx.x;
  const int n0  = blockIdx.x * 4;

  if (tid < 4) s_inv[tid] = 1.0f / fmaxf(cnt_h[n0 + tid], 1.0f);
  __syncthreads();

  for (int idx = tid; idx < 4 * D_OUT; idx += 128) {
    int j = idx >> 7;
    int k = idx & 127;
    int n = n0 + j;
    s_msg[j][k] = node_acc[(size_t)n * D_OUT + k] * s_inv[j];
    s_x[j][k]   = x_h[(size_t)n * D_H + k];
  }
  __syncthreads();

  {
    float b = bn1[tid];
    float acc[4] = {b, b, b, b};
    const float* w = Wn1 + (size_t)tid * D_OUT;
#pragma unroll 4
    for (int k = 0; k < D_OUT; ++k) {
      float wv = w[k];
#pragma unroll
      for (int j = 0; j < 4; ++j) acc[j] += wv * s_msg[j][k];
    }
#pragma unroll
    for (int j = 0; j < 4; ++j) s_t[j][tid] = fmaxf(acc[j], 0.0f);
  }
  __syncthreads();

  {
    float b = bp[tid] + bn2[tid];
    float acc[4] = {b, b, b, b};
    const float* wp = Wp  + (size_t)tid * D_H;
    const float* wn = Wn2 + (size_t)tid * D_OUT;
#pragma unroll 2
    for (int k = 0; k < D_OUT; ++k) {
      float wpv = wp[k];
      float wnv = wn[k];
#pragma unroll
      for (int j = 0; j < 4; ++j) acc[j] += wpv * s_x[j][k] + wnv * s_t[j][k];
    }
#pragma unroll
    for (int j = 0; j < 4; ++j) s_z[j][tid] = fmaxf(acc[j], 0.0f);
  }
  __syncthreads();

  // LayerNorm stats: 2 waves, each handles 2 nodes.
  {
    int w    = tid >> 6;
    int lane = tid & 63;
    for (int j = w; j < 4; j += 2) {
      float v1 = s_z[j][lane];
      float v2 = s_z[j][lane + 64];
      float s  = v1 + v2;
      float ss = v1 * v1 + v2 * v2;
#pragma unroll
      for (int off = 32; off > 0; off >>= 1) {
        s  += __shfl_xor(s, off, 64);
        ss += __shfl_xor(ss, off, 64);
      }
      if (lane == 0) {
        float mean = s * (1.0f / D_OUT);
        float var  = ss * (1.0f / D_OUT) - mean * mean;
        s_stat[j][0] = mean;
        s_stat[j][1] = rsqrtf(var + LN_EPS);
      }
    }
  }
  __syncthreads();

  for (int idx = tid; idx < 4 * D_OUT; idx += 128) {
    int j = idx >> 7;
    int k = idx & 127;
    out[(size_t)(n0 + j) * D_OUT + k] =
        (s_z[j][k] - s_stat[j][0]) * s_stat[j][1] * gamma[k] + beta[k];
  }
}

// ---------------------------------------------------------------------------
extern "C" void kernel_launch(void* const* d_in, const int* in_sizes, int n_in,
                              void* d_out, int out_size, void* d_ws, size_t ws_size,
                              hipStream_t stream) {
  const float* x_h   = (const float*)d_in[0];
  const float* attr  = (const float*)d_in[1];
  const float* Wp    = (const float*)d_in[2];
  const float* bp    = (const float*)d_in[3];
  const float* We1   = (const float*)d_in[4];
  const float* be1   = (const float*)d_in[5];
  const float* We2   = (const float*)d_in[6];
  const float* be2   = (const float*)d_in[7];
  const float* Wn1   = (const float*)d_in[8];
  const float* bn1   = (const float*)d_in[9];
  const float* Wn2   = (const float*)d_in[10];
  const float* bn2   = (const float*)d_in[11];
  const float* gamma = (const float*)d_in[12];
  const float* beta  = (const float*)d_in[13];
  const int*   fg    = (const int*)d_in[14];
  const int*   res   = (const int*)d_in[15];
  float* out = (float*)d_out;

  // Workspace layout (floats):
  //   edge_buf : E*128   (scatter accum, then edge_msg in place)
  //   node_acc : H*128
  //   cnt_e    : E
  //   cnt_h    : H
  float* ws       = (float*)d_ws;
  float* edge_buf = ws;
  float* node_acc = edge_buf + (size_t)E_N * D_H;
  float* cnt_e    = node_acc + (size_t)H_N * D_OUT;
  float* cnt_h    = cnt_e + E_N;
  size_t total_f  = (size_t)E_N * D_H + (size_t)H_N * D_OUT + E_N + H_N;

  hipMemsetAsync(d_ws, 0, total_f * sizeof(float), stream);

  k_scatter_n2e<<<NI_N / 4, 256, 0, stream>>>(x_h, fg, res, edge_buf, cnt_e);
  k_edge_mlp<<<E_N / 4, 128, 0, stream>>>(attr, We1, be1, We2, be2, edge_buf, cnt_e);
  k_scatter_e2n<<<NI_N / 4, 256, 0, stream>>>(edge_buf, fg, res, node_acc, cnt_h);
  k_node_mlp_ln<<<H_N / 4, 128, 0, stream>>>(x_h, node_acc, cnt_h,
                                             Wp, bp, Wn1, bn1, Wn2, bn2,
                                             gamma, beta, out);
}

// Round 2
// 2133.307 us; speedup vs baseline: 2.3731x; 2.3731x over previous
//
#include <hip/hip_runtime.h>

#define H_N   100000
#define E_N   200000
#define NI_N  1000000
#define LN_EPS 1e-5f

typedef __attribute__((ext_vector_type(8))) short bf16x8;
typedef __attribute__((ext_vector_type(4))) float floatx4;

__device__ inline unsigned short f2bf(float f) {
  unsigned u = __builtin_bit_cast(unsigned, f);
  u += 0x7fffu + ((u >> 16) & 1u);           // round-to-nearest-even
  return (unsigned short)(u >> 16);
}
__device__ inline float bf2f(unsigned short s) {
  unsigned u = ((unsigned)s) << 16;
  return __builtin_bit_cast(float, u);
}

// ---------------------------------------------------------------------------
// fp32 -> bf16 conversion, 4 elements/thread (n must be %4)
// ---------------------------------------------------------------------------
__global__ __launch_bounds__(256) void k_cvt_bf16(const float4* __restrict__ src,
                                                  unsigned short* __restrict__ dst,
                                                  int n4) {
  int i = blockIdx.x * 256 + threadIdx.x;
  if (i >= n4) return;
  float4 v = src[i];
  union { unsigned short us[4]; unsigned long long u64; } p;
  p.us[0] = f2bf(v.x); p.us[1] = f2bf(v.y);
  p.us[2] = f2bf(v.z); p.us[3] = f2bf(v.w);
  *(unsigned long long*)(dst + (size_t)i * 4) = p.u64;
}

// ---------------------------------------------------------------------------
// K1: node -> edge scatter-add (bf16 gather, HW fp32 atomics)
// ---------------------------------------------------------------------------
__global__ __launch_bounds__(256) void k_scatter_n2e(
    const unsigned short* __restrict__ xh_bf, const int* __restrict__ fg,
    const int* __restrict__ res, float* __restrict__ edge_acc,
    float* __restrict__ cnt_e) {
  int inc  = blockIdx.x * 4 + (threadIdx.x >> 6);
  int lane = threadIdx.x & 63;
  int f = fg[inc];
  int r = res[inc];
  unsigned v = *(const unsigned*)(xh_bf + (size_t)f * 128 + lane * 2);
  float* dst = edge_acc + (size_t)r * 128 + lane * 2;
  unsafeAtomicAdd(dst,     bf2f((unsigned short)(v & 0xffffu)));
  unsafeAtomicAdd(dst + 1, bf2f((unsigned short)(v >> 16)));
  if (lane == 0) unsafeAtomicAdd(cnt_e + r, 1.0f);
}

// ---------------------------------------------------------------------------
// K2: fused edge MLP via MFMA. Wave = 16 edges x 128 outputs.
//     A-frag: A[m=lane&15][k=quad*8+j]; B-frag: B[k][n=lane&15] = W[n][k]
//     C/D: col=lane&15, row=quad*4+reg.
// ---------------------------------------------------------------------------
__global__ __launch_bounds__(256) void k_edge_mlp(
    const float* __restrict__ edge_acc, const float* __restrict__ cnt_e,
    const float* __restrict__ attr,
    const short* __restrict__ w1, const float* __restrict__ b1,
    const short* __restrict__ w2, const float* __restrict__ b2,
    unsigned short* __restrict__ edge_msg) {
  __shared__ short h1s[4][16][136];   // +8 shorts pad: row stride 272B
  const int wave = threadIdx.x >> 6;
  const int lane = threadIdx.x & 63;
  const int row  = lane & 15;
  const int quad = lane >> 4;
  const int e0   = blockIdx.x * 64 + wave * 16;
  const int e    = e0 + row;
  const float inv = 1.0f / fmaxf(cnt_e[e], 1.0f);

  floatx4 acc[8];
#pragma unroll
  for (int nt = 0; nt < 8; ++nt) acc[nt] = (floatx4){0.f, 0.f, 0.f, 0.f};

#pragma unroll
  for (int ks = 0; ks < 6; ++ks) {
    bf16x8 a;
    if (ks < 4) {
      const float4* p = (const float4*)(edge_acc + (size_t)e * 128 + ks * 32 + quad * 8);
      float4 u0 = p[0], u1 = p[1];
      a[0] = (short)f2bf(u0.x * inv); a[1] = (short)f2bf(u0.y * inv);
      a[2] = (short)f2bf(u0.z * inv); a[3] = (short)f2bf(u0.w * inv);
      a[4] = (short)f2bf(u1.x * inv); a[5] = (short)f2bf(u1.y * inv);
      a[6] = (short)f2bf(u1.z * inv); a[7] = (short)f2bf(u1.w * inv);
    } else {
      const float4* p = (const float4*)(attr + (size_t)e * 64 + (ks - 4) * 32 + quad * 8);
      float4 u0 = p[0], u1 = p[1];
      a[0] = (short)f2bf(u0.x); a[1] = (short)f2bf(u0.y);
      a[2] = (short)f2bf(u0.z); a[3] = (short)f2bf(u0.w);
      a[4] = (short)f2bf(u1.x); a[5] = (short)f2bf(u1.y);
      a[6] = (short)f2bf(u1.z); a[7] = (short)f2bf(u1.w);
    }
#pragma unroll
    for (int nt = 0; nt < 8; ++nt) {
      bf16x8 b = *(const bf16x8*)(w1 + (size_t)(nt * 16 + row) * 192 + ks * 32 + quad * 8);
      acc[nt] = __builtin_amdgcn_mfma_f32_16x16x32_bf16(a, b, acc[nt], 0, 0, 0);
    }
  }

#pragma unroll
  for (int nt = 0; nt < 8; ++nt) {
    float bias = b1[nt * 16 + row];
#pragma unroll
    for (int r = 0; r < 4; ++r)
      h1s[wave][quad * 4 + r][nt * 16 + row] =
          (short)f2bf(fmaxf(acc[nt][r] + bias, 0.0f));
  }
  __syncthreads();

  floatx4 acc2[8];
#pragma unroll
  for (int nt = 0; nt < 8; ++nt) acc2[nt] = (floatx4){0.f, 0.f, 0.f, 0.f};
#pragma unroll
  for (int ks = 0; ks < 4; ++ks) {
    bf16x8 a = *(const bf16x8*)&h1s[wave][row][ks * 32 + quad * 8];
#pragma unroll
    for (int nt = 0; nt < 8; ++nt) {
      bf16x8 b = *(const bf16x8*)(w2 + (size_t)(nt * 16 + row) * 128 + ks * 32 + quad * 8);
      acc2[nt] = __builtin_amdgcn_mfma_f32_16x16x32_bf16(a, b, acc2[nt], 0, 0, 0);
    }
  }
#pragma unroll
  for (int nt = 0; nt < 8; ++nt) {
    float bias = b2[nt * 16 + row];
#pragma unroll
    for (int r = 0; r < 4; ++r)
      edge_msg[(size_t)(e0 + quad * 4 + r) * 128 + nt * 16 + row] =
          f2bf(acc2[nt][r] + bias);
  }
}

// ---------------------------------------------------------------------------
// K3: edge -> node scatter-add of bf16 edge messages
// ---------------------------------------------------------------------------
__global__ __launch_bounds__(256) void k_scatter_e2n(
    const unsigned short* __restrict__ edge_msg, const int* __restrict__ fg,
    const int* __restrict__ res, float* __restrict__ node_acc,
    float* __restrict__ cnt_h) {
  int inc  = blockIdx.x * 4 + (threadIdx.x >> 6);
  int lane = threadIdx.x & 63;
  int f = fg[inc];
  int r = res[inc];
  unsigned v = *(const unsigned*)(edge_msg + (size_t)r * 128 + lane * 2);
  float* dst = node_acc + (size_t)f * 128 + lane * 2;
  unsafeAtomicAdd(dst,     bf2f((unsigned short)(v & 0xffffu)));
  unsafeAtomicAdd(dst + 1, bf2f((unsigned short)(v >> 16)));
  if (lane == 0) unsafeAtomicAdd(cnt_h + f, 1.0f);
}

// ---------------------------------------------------------------------------
// K4: node MLP (Wn2*relu(Wn1*msg+bn1) + Wp*x + biases) + relu + LayerNorm
// ---------------------------------------------------------------------------
__global__ __launch_bounds__(256) void k_node_mlp_ln(
    const float* __restrict__ node_acc, const float* __restrict__ cnt_h,
    const unsigned short* __restrict__ xh_bf,
    const short* __restrict__ wp, const float* __restrict__ bp,
    const short* __restrict__ wn1, const float* __restrict__ bn1,
    const short* __restrict__ wn2, const float* __restrict__ bn2,
    const float* __restrict__ gamma, const float* __restrict__ beta,
    float* __restrict__ out) {
  __shared__ short h1s[4][16][136];
  const int wave = threadIdx.x >> 6;
  const int lane = threadIdx.x & 63;
  const int row  = lane & 15;
  const int quad = lane >> 4;
  const int n0   = blockIdx.x * 64 + wave * 16;
  const int e    = n0 + row;     // may exceed H_N in last block; reads stay in ws
  const float inv = 1.0f / fmaxf(cnt_h[e], 1.0f);

  floatx4 acc[8];
#pragma unroll
  for (int nt = 0; nt < 8; ++nt) acc[nt] = (floatx4){0.f, 0.f, 0.f, 0.f};
#pragma unroll
  for (int ks = 0; ks < 4; ++ks) {
    const float4* p = (const float4*)(node_acc + (size_t)e * 128 + ks * 32 + quad * 8);
    float4 u0 = p[0], u1 = p[1];
    bf16x8 a;
    a[0] = (short)f2bf(u0.x * inv); a[1] = (short)f2bf(u0.y * inv);
    a[2] = (short)f2bf(u0.z * inv); a[3] = (short)f2bf(u0.w * inv);
    a[4] = (short)f2bf(u1.x * inv); a[5] = (short)f2bf(u1.y * inv);
    a[6] = (short)f2bf(u1.z * inv); a[7] = (short)f2bf(u1.w * inv);
#pragma unroll
    for (int nt = 0; nt < 8; ++nt) {
      bf16x8 b = *(const bf16x8*)(wn1 + (size_t)(nt * 16 + row) * 128 + ks * 32 + quad * 8);
      acc[nt] = __builtin_amdgcn_mfma_f32_16x16x32_bf16(a, b, acc[nt], 0, 0, 0);
    }
  }
#pragma unroll
  for (int nt = 0; nt < 8; ++nt) {
    float bias = bn1[nt * 16 + row];
#pragma unroll
    for (int r = 0; r < 4; ++r)
      h1s[wave][quad * 4 + r][nt * 16 + row] =
          (short)f2bf(fmaxf(acc[nt][r] + bias, 0.0f));
  }
  __syncthreads();

  floatx4 acc2[8];
#pragma unroll
  for (int nt = 0; nt < 8; ++nt) acc2[nt] = (floatx4){0.f, 0.f, 0.f, 0.f};
#pragma unroll
  for (int ks = 0; ks < 4; ++ks) {
    bf16x8 at = *(const bf16x8*)&h1s[wave][row][ks * 32 + quad * 8];
    bf16x8 ax = *(const bf16x8*)(xh_bf + (size_t)e * 128 + ks * 32 + quad * 8);
#pragma unroll
    for (int nt = 0; nt < 8; ++nt) {
      bf16x8 b2v = *(const bf16x8*)(wn2 + (size_t)(nt * 16 + row) * 128 + ks * 32 + quad * 8);
      bf16x8 bpv = *(const bf16x8*)(wp  + (size_t)(nt * 16 + row) * 128 + ks * 32 + quad * 8);
      acc2[nt] = __builtin_amdgcn_mfma_f32_16x16x32_bf16(at, b2v, acc2[nt], 0, 0, 0);
      acc2[nt] = __builtin_amdgcn_mfma_f32_16x16x32_bf16(ax, bpv, acc2[nt], 0, 0, 0);
    }
  }

  // z = relu(acc2 + bp + bn2); LayerNorm over the 128 cols of each row.
  float z[8][4];
  float s[4]  = {0.f, 0.f, 0.f, 0.f};
  float s2[4] = {0.f, 0.f, 0.f, 0.f};
#pragma unroll
  for (int nt = 0; nt < 8; ++nt) {
    float bias = bp[nt * 16 + row] + bn2[nt * 16 + row];
#pragma unroll
    for (int r = 0; r < 4; ++r) {
      float v = fmaxf(acc2[nt][r] + bias, 0.0f);
      z[nt][r] = v;
      s[r]  += v;
      s2[r] += v * v;
    }
  }
#pragma unroll
  for (int r = 0; r < 4; ++r) {
#pragma unroll
    for (int m = 1; m < 16; m <<= 1) {
      s[r]  += __shfl_xor(s[r],  m, 64);
      s2[r] += __shfl_xor(s2[r], m, 64);
    }
  }
  float mean[4], rstd[4];
#pragma unroll
  for (int r = 0; r < 4; ++r) {
    mean[r] = s[r] * (1.0f / 128.0f);
    float var = s2[r] * (1.0f / 128.0f) - mean[r] * mean[r];
    rstd[r] = rsqrtf(var + LN_EPS);
  }
#pragma unroll
  for (int nt = 0; nt < 8; ++nt) {
    int col = nt * 16 + row;
    float g = gamma[col], bt = beta[col];
#pragma unroll
    for (int r = 0; r < 4; ++r) {
      int n = n0 + quad * 4 + r;
      if (n < H_N)
        out[(size_t)n * 128 + col] = (z[nt][r] - mean[r]) * rstd[r] * g + bt;
    }
  }
}

// ---------------------------------------------------------------------------
extern "C" void kernel_launch(void* const* d_in, const int* in_sizes, int n_in,
                              void* d_out, int out_size, void* d_ws, size_t ws_size,
                              hipStream_t stream) {
  const float* x_h   = (const float*)d_in[0];
  const float* attr  = (const float*)d_in[1];
  const float* Wp    = (const float*)d_in[2];
  const float* bp    = (const float*)d_in[3];
  const float* We1   = (const float*)d_in[4];
  const float* be1   = (const float*)d_in[5];
  const float* We2   = (const float*)d_in[6];
  const float* be2   = (const float*)d_in[7];
  const float* Wn1   = (const float*)d_in[8];
  const float* bn1   = (const float*)d_in[9];
  const float* Wn2   = (const float*)d_in[10];
  const float* bn2   = (const float*)d_in[11];
  const float* gamma = (const float*)d_in[12];
  const float* beta  = (const float*)d_in[13];
  const int*   fg    = (const int*)d_in[14];
  const int*   res   = (const int*)d_in[15];
  float* out = (float*)d_out;

  // Workspace layout (all offsets 64B-aligned):
  float* edge_acc = (float*)d_ws;                       // E*128 f32
  float* node_acc = edge_acc + (size_t)E_N * 128;       // H*128 f32
  float* cnt_e    = node_acc + (size_t)H_N * 128;       // E f32
  float* cnt_h    = cnt_e + E_N;                        // H f32
  unsigned short* edge_msg = (unsigned short*)(cnt_h + H_N);   // E*128 bf16
  unsigned short* xh_bf    = edge_msg + (size_t)E_N * 128;     // H*128 bf16
  short* w1  = (short*)(xh_bf + (size_t)H_N * 128);     // 128*192 bf16
  short* w2  = w1 + 128 * 192;                          // 128*128 bf16
  short* wn1 = w2 + 128 * 128;
  short* wn2 = wn1 + 128 * 128;
  short* wp  = wn2 + 128 * 128;

  size_t zero_bytes = ((size_t)E_N * 128 + (size_t)H_N * 128 + E_N + H_N) * 4;
  hipMemsetAsync(d_ws, 0, zero_bytes, stream);

  // fp32 -> bf16 conversions (x_h + the five weight matrices)
  {
    int n4 = H_N * 128 / 4;
    k_cvt_bf16<<<(n4 + 255) / 256, 256, 0, stream>>>((const float4*)x_h, xh_bf, n4);
    n4 = 128 * 192 / 4;
    k_cvt_bf16<<<(n4 + 255) / 256, 256, 0, stream>>>((const float4*)We1, (unsigned short*)w1, n4);
    n4 = 128 * 128 / 4;
    k_cvt_bf16<<<(n4 + 255) / 256, 256, 0, stream>>>((const float4*)We2, (unsigned short*)w2, n4);
    k_cvt_bf16<<<(n4 + 255) / 256, 256, 0, stream>>>((const float4*)Wn1, (unsigned short*)wn1, n4);
    k_cvt_bf16<<<(n4 + 255) / 256, 256, 0, stream>>>((const float4*)Wn2, (unsigned short*)wn2, n4);
    k_cvt_bf16<<<(n4 + 255) / 256, 256, 0, stream>>>((const float4*)Wp, (unsigned short*)wp, n4);
  }

  k_scatter_n2e<<<NI_N / 4, 256, 0, stream>>>(xh_bf, fg, res, edge_acc, cnt_e);
  k_edge_mlp<<<E_N / 64, 256, 0, stream>>>(edge_acc, cnt_e, attr,
                                           w1, be1, w2, be2, edge_msg);
  k_scatter_e2n<<<NI_N / 4, 256, 0, stream>>>(edge_msg, fg, res, node_acc, cnt_h);
  k_node_mlp_ln<<<(H_N + 63) / 64, 256, 0, stream>>>(node_acc, cnt_h, xh_bf,
                                                     wp, bp, wn1, bn1, wn2, bn2,
                                                     gamma, beta, out);
}

// Round 3
// 778.019 us; speedup vs baseline: 6.5069x; 2.7420x over previous
//
#include <hip/hip_runtime.h>

#define H_N   100000
#define E_N   200000
#define NI_N  1000000
#define LN_EPS 1e-5f

typedef __attribute__((ext_vector_type(8))) short bf16x8;
typedef __attribute__((ext_vector_type(4))) float floatx4;

__device__ inline unsigned short f2bf(float f) {
  unsigned u = __builtin_bit_cast(unsigned, f);
  u += 0x7fffu + ((u >> 16) & 1u);           // round-to-nearest-even
  return (unsigned short)(u >> 16);
}
__device__ inline float bf2f(unsigned short s) {
  unsigned u = ((unsigned)s) << 16;
  return __builtin_bit_cast(float, u);
}

// ---------------------------------------------------------------------------
// fp32 -> bf16 conversion, 4 elements/thread
// ---------------------------------------------------------------------------
__global__ __launch_bounds__(256) void k_cvt_bf16(const float4* __restrict__ src,
                                                  unsigned short* __restrict__ dst,
                                                  int n4) {
  int i = blockIdx.x * 256 + threadIdx.x;
  if (i >= n4) return;
  float4 v = src[i];
  union { unsigned short us[4]; unsigned long long u64; } p;
  p.us[0] = f2bf(v.x); p.us[1] = f2bf(v.y);
  p.us[2] = f2bf(v.z); p.us[3] = f2bf(v.w);
  *(unsigned long long*)(dst + (size_t)i * 4) = p.u64;
}

// ---------------------------------------------------------------------------
// CSR build: histogram -> exclusive scan (3 kernels) -> permutation fill
// ---------------------------------------------------------------------------
__global__ __launch_bounds__(256) void k_hist(const int* __restrict__ fg,
                                              const int* __restrict__ res,
                                              int* __restrict__ hist_h,
                                              int* __restrict__ hist_e) {
  int i = blockIdx.x * 256 + threadIdx.x;
  if (i >= NI_N) return;
  atomicAdd(hist_e + res[i], 1);
  atomicAdd(hist_h + fg[i], 1);
}

// exclusive scan of 2048 elements per block; block totals to bsum
__global__ __launch_bounds__(256) void k_scan1(const int* __restrict__ in,
                                               int* __restrict__ out,
                                               int* __restrict__ bsum, int n) {
  __shared__ int s[256];
  const int base = blockIdx.x * 2048;
  const int t = threadIdx.x;
  int v[8]; int sum = 0;
#pragma unroll
  for (int k = 0; k < 8; ++k) {
    int i = base + t * 8 + k;
    v[k] = (i < n) ? in[i] : 0;
    sum += v[k];
  }
  s[t] = sum;
  __syncthreads();
  for (int off = 1; off < 256; off <<= 1) {
    int x = (t >= off) ? s[t - off] : 0;
    __syncthreads();
    s[t] += x;
    __syncthreads();
  }
  int run = s[t] - sum;          // exclusive prefix for this thread
  if (t == 255) bsum[blockIdx.x] = s[255];
#pragma unroll
  for (int k = 0; k < 8; ++k) {
    int i = base + t * 8 + k;
    if (i < n) out[i] = run;
    run += v[k];
  }
}

// single-block exclusive scan of block sums (nb <= 128)
__global__ __launch_bounds__(128) void k_scan2(int* __restrict__ bsum, int nb) {
  __shared__ int s[128];
  int t = threadIdx.x;
  int v = (t < nb) ? bsum[t] : 0;
  s[t] = v;
  __syncthreads();
  for (int off = 1; off < 128; off <<= 1) {
    int x = (t >= off) ? s[t - off] : 0;
    __syncthreads();
    s[t] += x;
    __syncthreads();
  }
  if (t < nb) bsum[t] = s[t] - v;
}

__global__ __launch_bounds__(256) void k_scan3(int* __restrict__ outv,
                                               const int* __restrict__ bsum,
                                               int n, int total) {
  const int base = blockIdx.x * 2048;
  const int add = bsum[blockIdx.x];
  for (int k = threadIdx.x; k < 2048; k += 256) {
    int i = base + k;
    if (i < n) outv[i] += add;
  }
  if (blockIdx.x == 0 && threadIdx.x == 0) outv[n] = total;
}

// fill permutations: perm_e[slot in edge-segment] = node idx,
//                    perm_h[slot in node-segment] = edge idx
__global__ __launch_bounds__(256) void k_perm(const int* __restrict__ fg,
                                              const int* __restrict__ res,
                                              const int* __restrict__ off_e,
                                              const int* __restrict__ off_h,
                                              int* __restrict__ cur_e,
                                              int* __restrict__ cur_h,
                                              int* __restrict__ perm_e,
                                              int* __restrict__ perm_h) {
  int i = blockIdx.x * 256 + threadIdx.x;
  if (i >= NI_N) return;
  int f = fg[i], r = res[i];
  int pe = off_e[r] + atomicAdd(cur_e + r, 1);
  perm_e[pe] = f;
  int ph = off_h[f] + atomicAdd(cur_h + f, 1);
  perm_h[ph] = r;
}

// ---------------------------------------------------------------------------
// Segment mean via gather: one wave per segment, 2 bf16 cols per lane.
// ---------------------------------------------------------------------------
__global__ __launch_bounds__(256) void k_gather_mean(
    const unsigned short* __restrict__ rows, const int* __restrict__ perm,
    const int* __restrict__ off, unsigned short* __restrict__ outm, int nseg) {
  int seg = blockIdx.x * 4 + (threadIdx.x >> 6);
  if (seg >= nseg) return;
  int lane = threadIdx.x & 63;
  int s = off[seg], e = off[seg + 1];
  int deg = e - s;
  float a0 = 0.f, a1 = 0.f;
  // prefetch up to 64 indices into the wave, broadcast via shuffle
  int pre = (s + lane < e) ? perm[s + lane] : 0;
  int n0 = deg < 64 ? deg : 64;
  for (int j = 0; j < n0; ++j) {
    int idx = __shfl(pre, j, 64);
    unsigned v = *(const unsigned*)(rows + (size_t)idx * 128 + lane * 2);
    a0 += bf2f((unsigned short)(v & 0xffffu));
    a1 += bf2f((unsigned short)(v >> 16));
  }
  for (int j = s + 64; j < e; ++j) {   // rare: deg > 64
    int idx = perm[j];
    unsigned v = *(const unsigned*)(rows + (size_t)idx * 128 + lane * 2);
    a0 += bf2f((unsigned short)(v & 0xffffu));
    a1 += bf2f((unsigned short)(v >> 16));
  }
  float inv = deg > 0 ? 1.0f / (float)deg : 0.0f;
  unsigned o = (unsigned)f2bf(a0 * inv) | ((unsigned)f2bf(a1 * inv) << 16);
  *(unsigned*)(outm + (size_t)seg * 128 + lane * 2) = o;
}

// ---------------------------------------------------------------------------
// Edge MLP via MFMA. Wave = 16 edges x 128 outputs. Input mean is bf16.
// ---------------------------------------------------------------------------
__global__ __launch_bounds__(256) void k_edge_mlp(
    const short* __restrict__ edge_mean, const float* __restrict__ attr,
    const short* __restrict__ w1, const float* __restrict__ b1,
    const short* __restrict__ w2, const float* __restrict__ b2,
    unsigned short* __restrict__ edge_msg) {
  __shared__ short h1s[4][16][136];   // +8 shorts pad
  const int wave = threadIdx.x >> 6;
  const int lane = threadIdx.x & 63;
  const int row  = lane & 15;
  const int quad = lane >> 4;
  const int e0   = blockIdx.x * 64 + wave * 16;
  const int e    = e0 + row;

  floatx4 acc[8];
#pragma unroll
  for (int nt = 0; nt < 8; ++nt) acc[nt] = (floatx4){0.f, 0.f, 0.f, 0.f};

#pragma unroll
  for (int ks = 0; ks < 6; ++ks) {
    bf16x8 a;
    if (ks < 4) {
      a = *(const bf16x8*)(edge_mean + (size_t)e * 128 + ks * 32 + quad * 8);
    } else {
      const float4* p = (const float4*)(attr + (size_t)e * 64 + (ks - 4) * 32 + quad * 8);
      float4 u0 = p[0], u1 = p[1];
      a[0] = (short)f2bf(u0.x); a[1] = (short)f2bf(u0.y);
      a[2] = (short)f2bf(u0.z); a[3] = (short)f2bf(u0.w);
      a[4] = (short)f2bf(u1.x); a[5] = (short)f2bf(u1.y);
      a[6] = (short)f2bf(u1.z); a[7] = (short)f2bf(u1.w);
    }
#pragma unroll
    for (int nt = 0; nt < 8; ++nt) {
      bf16x8 b = *(const bf16x8*)(w1 + (size_t)(nt * 16 + row) * 192 + ks * 32 + quad * 8);
      acc[nt] = __builtin_amdgcn_mfma_f32_16x16x32_bf16(a, b, acc[nt], 0, 0, 0);
    }
  }

#pragma unroll
  for (int nt = 0; nt < 8; ++nt) {
    float bias = b1[nt * 16 + row];
#pragma unroll
    for (int r = 0; r < 4; ++r)
      h1s[wave][quad * 4 + r][nt * 16 + row] =
          (short)f2bf(fmaxf(acc[nt][r] + bias, 0.0f));
  }
  __syncthreads();

  floatx4 acc2[8];
#pragma unroll
  for (int nt = 0; nt < 8; ++nt) acc2[nt] = (floatx4){0.f, 0.f, 0.f, 0.f};
#pragma unroll
  for (int ks = 0; ks < 4; ++ks) {
    bf16x8 a = *(const bf16x8*)&h1s[wave][row][ks * 32 + quad * 8];
#pragma unroll
    for (int nt = 0; nt < 8; ++nt) {
      bf16x8 b = *(const bf16x8*)(w2 + (size_t)(nt * 16 + row) * 128 + ks * 32 + quad * 8);
      acc2[nt] = __builtin_amdgcn_mfma_f32_16x16x32_bf16(a, b, acc2[nt], 0, 0, 0);
    }
  }
#pragma unroll
  for (int nt = 0; nt < 8; ++nt) {
    float bias = b2[nt * 16 + row];
#pragma unroll
    for (int r = 0; r < 4; ++r)
      edge_msg[(size_t)(e0 + quad * 4 + r) * 128 + nt * 16 + row] =
          f2bf(acc2[nt][r] + bias);
  }
}

// ---------------------------------------------------------------------------
// Node MLP + residual projection + relu + LayerNorm (bf16 msg input)
// ---------------------------------------------------------------------------
__global__ __launch_bounds__(256) void k_node_mlp_ln(
    const short* __restrict__ node_msg, const short* __restrict__ xh_bf,
    const short* __restrict__ wp, const float* __restrict__ bp,
    const short* __restrict__ wn1, const float* __restrict__ bn1,
    const short* __restrict__ wn2, const float* __restrict__ bn2,
    const float* __restrict__ gamma, const float* __restrict__ beta,
    float* __restrict__ out) {
  __shared__ short h1s[4][16][136];
  const int wave = threadIdx.x >> 6;
  const int lane = threadIdx.x & 63;
  const int row  = lane & 15;
  const int quad = lane >> 4;
  const int n0   = blockIdx.x * 64 + wave * 16;
  const int e    = n0 + row;   // last block over-reads into ws (valid memory)

  floatx4 acc[8];
#pragma unroll
  for (int nt = 0; nt < 8; ++nt) acc[nt] = (floatx4){0.f, 0.f, 0.f, 0.f};
#pragma unroll
  for (int ks = 0; ks < 4; ++ks) {
    bf16x8 a = *(const bf16x8*)(node_msg + (size_t)e * 128 + ks * 32 + quad * 8);
#pragma unroll
    for (int nt = 0; nt < 8; ++nt) {
      bf16x8 b = *(const bf16x8*)(wn1 + (size_t)(nt * 16 + row) * 128 + ks * 32 + quad * 8);
      acc[nt] = __builtin_amdgcn_mfma_f32_16x16x32_bf16(a, b, acc[nt], 0, 0, 0);
    }
  }
#pragma unroll
  for (int nt = 0; nt < 8; ++nt) {
    float bias = bn1[nt * 16 + row];
#pragma unroll
    for (int r = 0; r < 4; ++r)
      h1s[wave][quad * 4 + r][nt * 16 + row] =
          (short)f2bf(fmaxf(acc[nt][r] + bias, 0.0f));
  }
  __syncthreads();

  floatx4 acc2[8];
#pragma unroll
  for (int nt = 0; nt < 8; ++nt) acc2[nt] = (floatx4){0.f, 0.f, 0.f, 0.f};
#pragma unroll
  for (int ks = 0; ks < 4; ++ks) {
    bf16x8 at = *(const bf16x8*)&h1s[wave][row][ks * 32 + quad * 8];
    bf16x8 ax = *(const bf16x8*)(xh_bf + (size_t)e * 128 + ks * 32 + quad * 8);
#pragma unroll
    for (int nt = 0; nt < 8; ++nt) {
      bf16x8 b2v = *(const bf16x8*)(wn2 + (size_t)(nt * 16 + row) * 128 + ks * 32 + quad * 8);
      bf16x8 bpv = *(const bf16x8*)(wp  + (size_t)(nt * 16 + row) * 128 + ks * 32 + quad * 8);
      acc2[nt] = __builtin_amdgcn_mfma_f32_16x16x32_bf16(at, b2v, acc2[nt], 0, 0, 0);
      acc2[nt] = __builtin_amdgcn_mfma_f32_16x16x32_bf16(ax, bpv, acc2[nt], 0, 0, 0);
    }
  }

  float z[8][4];
  float s[4]  = {0.f, 0.f, 0.f, 0.f};
  float s2[4] = {0.f, 0.f, 0.f, 0.f};
#pragma unroll
  for (int nt = 0; nt < 8; ++nt) {
    float bias = bp[nt * 16 + row] + bn2[nt * 16 + row];
#pragma unroll
    for (int r = 0; r < 4; ++r) {
      float v = fmaxf(acc2[nt][r] + bias, 0.0f);
      z[nt][r] = v;
      s[r]  += v;
      s2[r] += v * v;
    }
  }
#pragma unroll
  for (int r = 0; r < 4; ++r) {
#pragma unroll
    for (int m = 1; m < 16; m <<= 1) {
      s[r]  += __shfl_xor(s[r],  m, 64);
      s2[r] += __shfl_xor(s2[r], m, 64);
    }
  }
  float mean[4], rstd[4];
#pragma unroll
  for (int r = 0; r < 4; ++r) {
    mean[r] = s[r] * (1.0f / 128.0f);
    float var = s2[r] * (1.0f / 128.0f) - mean[r] * mean[r];
    rstd[r] = rsqrtf(var + LN_EPS);
  }
#pragma unroll
  for (int nt = 0; nt < 8; ++nt) {
    int col = nt * 16 + row;
    float g = gamma[col], bt = beta[col];
#pragma unroll
    for (int r = 0; r < 4; ++r) {
      int n = n0 + quad * 4 + r;
      if (n < H_N)
        out[(size_t)n * 128 + col] = (z[nt][r] - mean[r]) * rstd[r] * g + bt;
    }
  }
}

// ---------------------------------------------------------------------------
extern "C" void kernel_launch(void* const* d_in, const int* in_sizes, int n_in,
                              void* d_out, int out_size, void* d_ws, size_t ws_size,
                              hipStream_t stream) {
  const float* x_h   = (const float*)d_in[0];
  const float* attr  = (const float*)d_in[1];
  const float* Wp    = (const float*)d_in[2];
  const float* bp    = (const float*)d_in[3];
  const float* We1   = (const float*)d_in[4];
  const float* be1   = (const float*)d_in[5];
  const float* We2   = (const float*)d_in[6];
  const float* be2   = (const float*)d_in[7];
  const float* Wn1   = (const float*)d_in[8];
  const float* bn1   = (const float*)d_in[9];
  const float* Wn2   = (const float*)d_in[10];
  const float* bn2   = (const float*)d_in[11];
  const float* gamma = (const float*)d_in[12];
  const float* beta  = (const float*)d_in[13];
  const int*   fg    = (const int*)d_in[14];
  const int*   res   = (const int*)d_in[15];
  float* out = (float*)d_out;

  // ---- workspace layout ----
  int* cur_e  = (int*)d_ws;                 // E   (histogram, then cursor)
  int* cur_h  = cur_e + E_N;                // H
  int* off_e  = cur_h + H_N;                // E+1
  int* off_h  = off_e + E_N + 1;            // H+1
  int* bsum_e = off_h + H_N + 1;            // 128
  int* bsum_h = bsum_e + 128;               // 128
  int* perm_e = bsum_h + 128;               // NI (stores node idx per edge-slot)
  int* perm_h = perm_e + NI_N;              // NI (stores edge idx per node-slot)
  uintptr_t pa = ((uintptr_t)(perm_h + NI_N) + 63) & ~(uintptr_t)63;
  unsigned short* xh_bf     = (unsigned short*)pa;          // H*128 bf16
  unsigned short* edge_mean = xh_bf + (size_t)H_N * 128;    // E*128 bf16
  unsigned short* edge_msg  = edge_mean + (size_t)E_N * 128;// E*128 bf16
  unsigned short* node_msg  = edge_msg + (size_t)E_N * 128; // H*128 bf16
  short* w1  = (short*)(node_msg + (size_t)H_N * 128);      // 128*192
  short* w2  = w1 + 128 * 192;
  short* wn1 = w2 + 128 * 128;
  short* wn2 = wn1 + 128 * 128;
  short* wp  = wn2 + 128 * 128;

  const int nb_e = (E_N + 2047) / 2048;   // 98
  const int nb_h = (H_N + 2047) / 2048;   // 49

  // zero histograms/cursors
  hipMemsetAsync(cur_e, 0, (size_t)(E_N + H_N) * 4, stream);

  // bf16 conversions
  {
    int n4 = H_N * 128 / 4;
    k_cvt_bf16<<<(n4 + 255) / 256, 256, 0, stream>>>((const float4*)x_h, xh_bf, n4);
    n4 = 128 * 192 / 4;
    k_cvt_bf16<<<(n4 + 255) / 256, 256, 0, stream>>>((const float4*)We1, (unsigned short*)w1, n4);
    n4 = 128 * 128 / 4;
    k_cvt_bf16<<<(n4 + 255) / 256, 256, 0, stream>>>((const float4*)We2, (unsigned short*)w2, n4);
    k_cvt_bf16<<<(n4 + 255) / 256, 256, 0, stream>>>((const float4*)Wn1, (unsigned short*)wn1, n4);
    k_cvt_bf16<<<(n4 + 255) / 256, 256, 0, stream>>>((const float4*)Wn2, (unsigned short*)wn2, n4);
    k_cvt_bf16<<<(n4 + 255) / 256, 256, 0, stream>>>((const float4*)Wp, (unsigned short*)wp, n4);
  }

  // CSR build
  k_hist<<<(NI_N + 255) / 256, 256, 0, stream>>>(fg, res, cur_h, cur_e);
  k_scan1<<<nb_e, 256, 0, stream>>>(cur_e, off_e, bsum_e, E_N);
  k_scan1<<<nb_h, 256, 0, stream>>>(cur_h, off_h, bsum_h, H_N);
  k_scan2<<<1, 128, 0, stream>>>(bsum_e, nb_e);
  k_scan2<<<1, 128, 0, stream>>>(bsum_h, nb_h);
  k_scan3<<<nb_e, 256, 0, stream>>>(off_e, bsum_e, E_N, NI_N);
  k_scan3<<<nb_h, 256, 0, stream>>>(off_h, bsum_h, H_N, NI_N);
  hipMemsetAsync(cur_e, 0, (size_t)(E_N + H_N) * 4, stream);
  k_perm<<<(NI_N + 255) / 256, 256, 0, stream>>>(fg, res, off_e, off_h,
                                                 cur_e, cur_h, perm_e, perm_h);

  // node -> edge mean, edge MLP
  k_gather_mean<<<(E_N + 3) / 4, 256, 0, stream>>>(xh_bf, perm_e, off_e,
                                                   edge_mean, E_N);
  k_edge_mlp<<<E_N / 64, 256, 0, stream>>>((const short*)edge_mean, attr,
                                           w1, be1, w2, be2, edge_msg);

  // edge -> node mean, node MLP + LN
  k_gather_mean<<<(H_N + 3) / 4, 256, 0, stream>>>(edge_msg, perm_h, off_h,
                                                   node_msg, H_N);
  k_node_mlp_ln<<<(H_N + 63) / 64, 256, 0, stream>>>((const short*)node_msg,
                                                     (const short*)xh_bf,
                                                     wp, bp, wn1, bn1, wn2, bn2,
                                                     gamma, beta, out);
}

// Round 4
// 700.702 us; speedup vs baseline: 7.2249x; 1.1103x over previous
//
#include <hip/hip_runtime.h>

#define H_N   100000
#define E_N   200000
#define NI_N  1000000
#define LN_EPS 1e-5f

typedef __attribute__((ext_vector_type(8))) short bf16x8;
typedef __attribute__((ext_vector_type(4))) float floatx4;

__device__ inline unsigned short f2bf(float f) {
  unsigned u = __builtin_bit_cast(unsigned, f);
  u += 0x7fffu + ((u >> 16) & 1u);           // round-to-nearest-even
  return (unsigned short)(u >> 16);
}
__device__ inline float bf2f(unsigned short s) {
  unsigned u = ((unsigned)s) << 16;
  return __builtin_bit_cast(float, u);
}

// ---------------------------------------------------------------------------
// fp32 -> bf16 conversion, 4 elements/thread
// ---------------------------------------------------------------------------
__global__ __launch_bounds__(256) void k_cvt_bf16(const float4* __restrict__ src,
                                                  unsigned short* __restrict__ dst,
                                                  int n4) {
  int i = blockIdx.x * 256 + threadIdx.x;
  if (i >= n4) return;
  float4 v = src[i];
  union { unsigned short us[4]; unsigned long long u64; } p;
  p.us[0] = f2bf(v.x); p.us[1] = f2bf(v.y);
  p.us[2] = f2bf(v.z); p.us[3] = f2bf(v.w);
  *(unsigned long long*)(dst + (size_t)i * 4) = p.u64;
}

// ---------------------------------------------------------------------------
// CSR build: histogram -> exclusive scan -> permutation fill
// ---------------------------------------------------------------------------
__global__ __launch_bounds__(256) void k_hist(const int* __restrict__ fg,
                                              const int* __restrict__ res,
                                              int* __restrict__ hist_h,
                                              int* __restrict__ hist_e) {
  int i = blockIdx.x * 256 + threadIdx.x;
  if (i >= NI_N) return;
  atomicAdd(hist_e + res[i], 1);
  atomicAdd(hist_h + fg[i], 1);
}

__global__ __launch_bounds__(256) void k_scan1(const int* __restrict__ in,
                                               int* __restrict__ out,
                                               int* __restrict__ bsum, int n) {
  __shared__ int s[256];
  const int base = blockIdx.x * 2048;
  const int t = threadIdx.x;
  int v[8]; int sum = 0;
#pragma unroll
  for (int k = 0; k < 8; ++k) {
    int i = base + t * 8 + k;
    v[k] = (i < n) ? in[i] : 0;
    sum += v[k];
  }
  s[t] = sum;
  __syncthreads();
  for (int off = 1; off < 256; off <<= 1) {
    int x = (t >= off) ? s[t - off] : 0;
    __syncthreads();
    s[t] += x;
    __syncthreads();
  }
  int run = s[t] - sum;
  if (t == 255) bsum[blockIdx.x] = s[255];
#pragma unroll
  for (int k = 0; k < 8; ++k) {
    int i = base + t * 8 + k;
    if (i < n) out[i] = run;
    run += v[k];
  }
}

__global__ __launch_bounds__(128) void k_scan2(int* __restrict__ bsum, int nb) {
  __shared__ int s[128];
  int t = threadIdx.x;
  int v = (t < nb) ? bsum[t] : 0;
  s[t] = v;
  __syncthreads();
  for (int off = 1; off < 128; off <<= 1) {
    int x = (t >= off) ? s[t - off] : 0;
    __syncthreads();
    s[t] += x;
    __syncthreads();
  }
  if (t < nb) bsum[t] = s[t] - v;
}

__global__ __launch_bounds__(256) void k_scan3(int* __restrict__ outv,
                                               const int* __restrict__ bsum,
                                               int n, int total) {
  const int base = blockIdx.x * 2048;
  const int add = bsum[blockIdx.x];
  for (int k = threadIdx.x; k < 2048; k += 256) {
    int i = base + k;
    if (i < n) outv[i] += add;
  }
  if (blockIdx.x == 0 && threadIdx.x == 0) outv[n] = total;
}

__global__ __launch_bounds__(256) void k_perm(const int* __restrict__ fg,
                                              const int* __restrict__ res,
                                              const int* __restrict__ off_e,
                                              const int* __restrict__ off_h,
                                              int* __restrict__ cur_e,
                                              int* __restrict__ cur_h,
                                              int* __restrict__ perm_e,
                                              int* __restrict__ perm_h) {
  int i = blockIdx.x * 256 + threadIdx.x;
  if (i >= NI_N) return;
  int f = fg[i], r = res[i];
  int pe = off_e[r] + atomicAdd(cur_e + r, 1);
  perm_e[pe] = f;
  int ph = off_h[f] + atomicAdd(cur_h + f, 1);
  perm_h[ph] = r;
}

// ---------------------------------------------------------------------------
// Segment mean via gather: one wave per segment, 2 bf16 cols per lane.
// ---------------------------------------------------------------------------
__global__ __launch_bounds__(256) void k_gather_mean(
    const unsigned short* __restrict__ rows, const int* __restrict__ perm,
    const int* __restrict__ off, unsigned short* __restrict__ outm, int nseg) {
  int seg = blockIdx.x * 4 + (threadIdx.x >> 6);
  if (seg >= nseg) return;
  int lane = threadIdx.x & 63;
  int s = off[seg], e = off[seg + 1];
  int deg = e - s;
  float a0 = 0.f, a1 = 0.f;
  int pre = (s + lane < e) ? perm[s + lane] : 0;
  int n0 = deg < 64 ? deg : 64;
  for (int j = 0; j < n0; ++j) {
    int idx = __shfl(pre, j, 64);
    unsigned v = *(const unsigned*)(rows + (size_t)idx * 128 + lane * 2);
    a0 += bf2f((unsigned short)(v & 0xffffu));
    a1 += bf2f((unsigned short)(v >> 16));
  }
  for (int j = s + 64; j < e; ++j) {
    int idx = perm[j];
    unsigned v = *(const unsigned*)(rows + (size_t)idx * 128 + lane * 2);
    a0 += bf2f((unsigned short)(v & 0xffffu));
    a1 += bf2f((unsigned short)(v >> 16));
  }
  float inv = deg > 0 ? 1.0f / (float)deg : 0.0f;
  unsigned o = (unsigned)f2bf(a0 * inv) | ((unsigned)f2bf(a1 * inv) << 16);
  *(unsigned*)(outm + (size_t)seg * 128 + lane * 2) = o;
}

// ---------------------------------------------------------------------------
// Edge MLP, N-split: block = 64 edges, each wave owns 32 output cols.
// B-frags (weight slices) live in registers, loaded ONCE per wave.
// ---------------------------------------------------------------------------
__global__ __launch_bounds__(256) void k_edge_mlp(
    const short* __restrict__ edge_mean, const float* __restrict__ attr,
    const short* __restrict__ w1, const float* __restrict__ b1,
    const short* __restrict__ w2, const float* __restrict__ b2,
    unsigned short* __restrict__ edge_msg) {
  __shared__ short h1s[64][136];            // +8 pad: row stride 272 B
  const int wave = threadIdx.x >> 6;
  const int lane = threadIdx.x & 63;
  const int row  = lane & 15;
  const int quad = lane >> 4;
  const int e0   = blockIdx.x * 64;
  const int cb   = wave * 32;               // this wave's output col base

  // W1 slice: 2 col-tiles x 6 k-steps, resident in VGPRs
  bf16x8 B1[2][6];
#pragma unroll
  for (int nl = 0; nl < 2; ++nl)
#pragma unroll
    for (int ks = 0; ks < 6; ++ks)
      B1[nl][ks] = *(const bf16x8*)(w1 + (size_t)(cb + nl * 16 + row) * 192 +
                                    ks * 32 + quad * 8);

  floatx4 acc[4][2];
#pragma unroll
  for (int m = 0; m < 4; ++m)
#pragma unroll
    for (int nl = 0; nl < 2; ++nl) acc[m][nl] = (floatx4){0.f, 0.f, 0.f, 0.f};

#pragma unroll
  for (int ks = 0; ks < 6; ++ks) {
    bf16x8 a[4];
#pragma unroll
    for (int m = 0; m < 4; ++m) {
      int e = e0 + m * 16 + row;
      if (ks < 4) {
        a[m] = *(const bf16x8*)(edge_mean + (size_t)e * 128 + ks * 32 + quad * 8);
      } else {
        const float4* p = (const float4*)(attr + (size_t)e * 64 +
                                          (ks - 4) * 32 + quad * 8);
        float4 u0 = p[0], u1 = p[1];
        a[m][0] = (short)f2bf(u0.x); a[m][1] = (short)f2bf(u0.y);
        a[m][2] = (short)f2bf(u0.z); a[m][3] = (short)f2bf(u0.w);
        a[m][4] = (short)f2bf(u1.x); a[m][5] = (short)f2bf(u1.y);
        a[m][6] = (short)f2bf(u1.z); a[m][7] = (short)f2bf(u1.w);
      }
    }
#pragma unroll
    for (int m = 0; m < 4; ++m)
#pragma unroll
      for (int nl = 0; nl < 2; ++nl)
        acc[m][nl] = __builtin_amdgcn_mfma_f32_16x16x32_bf16(a[m], B1[nl][ks],
                                                             acc[m][nl], 0, 0, 0);
  }

  // h1 -> LDS (C-layout write, A-layout read after sync)
#pragma unroll
  for (int nl = 0; nl < 2; ++nl) {
    float bias = b1[cb + nl * 16 + row];
#pragma unroll
    for (int m = 0; m < 4; ++m)
#pragma unroll
      for (int r = 0; r < 4; ++r)
        h1s[m * 16 + quad * 4 + r][cb + nl * 16 + row] =
            (short)f2bf(fmaxf(acc[m][nl][r] + bias, 0.0f));
  }

  // W2 slice (overlaps the barrier wait)
  bf16x8 B2[2][4];
#pragma unroll
  for (int nl = 0; nl < 2; ++nl)
#pragma unroll
    for (int ks = 0; ks < 4; ++ks)
      B2[nl][ks] = *(const bf16x8*)(w2 + (size_t)(cb + nl * 16 + row) * 128 +
                                    ks * 32 + quad * 8);
  __syncthreads();

  floatx4 acc2[4][2];
#pragma unroll
  for (int m = 0; m < 4; ++m)
#pragma unroll
    for (int nl = 0; nl < 2; ++nl) acc2[m][nl] = (floatx4){0.f, 0.f, 0.f, 0.f};

#pragma unroll
  for (int ks = 0; ks < 4; ++ks) {
    bf16x8 a[4];
#pragma unroll
    for (int m = 0; m < 4; ++m)
      a[m] = *(const bf16x8*)&h1s[m * 16 + row][ks * 32 + quad * 8];
#pragma unroll
    for (int m = 0; m < 4; ++m)
#pragma unroll
      for (int nl = 0; nl < 2; ++nl)
        acc2[m][nl] = __builtin_amdgcn_mfma_f32_16x16x32_bf16(a[m], B2[nl][ks],
                                                              acc2[m][nl], 0, 0, 0);
  }

#pragma unroll
  for (int nl = 0; nl < 2; ++nl) {
    int col = cb + nl * 16 + row;
    float bias = b2[col];
#pragma unroll
    for (int m = 0; m < 4; ++m)
#pragma unroll
      for (int r = 0; r < 4; ++r)
        edge_msg[(size_t)(e0 + m * 16 + quad * 4 + r) * 128 + col] =
            f2bf(acc2[m][nl][r] + bias);
  }
}

// ---------------------------------------------------------------------------
// Node MLP + residual projection + relu + LayerNorm, N-split like k_edge_mlp.
// ---------------------------------------------------------------------------
__global__ __launch_bounds__(256) void k_node_mlp_ln(
    const short* __restrict__ node_msg, const short* __restrict__ xh_bf,
    const short* __restrict__ wp, const float* __restrict__ bp,
    const short* __restrict__ wn1, const float* __restrict__ bn1,
    const short* __restrict__ wn2, const float* __restrict__ bn2,
    const float* __restrict__ gamma, const float* __restrict__ beta,
    float* __restrict__ out) {
  __shared__ short h1s[64][136];
  __shared__ float2 part[64][4];            // per-row per-wave (sum, sumsq)
  const int wave = threadIdx.x >> 6;
  const int lane = threadIdx.x & 63;
  const int row  = lane & 15;
  const int quad = lane >> 4;
  const int n0   = blockIdx.x * 64;
  const int cb   = wave * 32;

  bf16x8 B1[2][4];
#pragma unroll
  for (int nl = 0; nl < 2; ++nl)
#pragma unroll
    for (int ks = 0; ks < 4; ++ks)
      B1[nl][ks] = *(const bf16x8*)(wn1 + (size_t)(cb + nl * 16 + row) * 128 +
                                    ks * 32 + quad * 8);

  floatx4 acc[4][2];
#pragma unroll
  for (int m = 0; m < 4; ++m)
#pragma unroll
    for (int nl = 0; nl < 2; ++nl) acc[m][nl] = (floatx4){0.f, 0.f, 0.f, 0.f};

#pragma unroll
  for (int ks = 0; ks < 4; ++ks) {
    bf16x8 a[4];
#pragma unroll
    for (int m = 0; m < 4; ++m) {
      int n = n0 + m * 16 + row;            // last block over-reads into ws
      a[m] = *(const bf16x8*)(node_msg + (size_t)n * 128 + ks * 32 + quad * 8);
    }
#pragma unroll
    for (int m = 0; m < 4; ++m)
#pragma unroll
      for (int nl = 0; nl < 2; ++nl)
        acc[m][nl] = __builtin_amdgcn_mfma_f32_16x16x32_bf16(a[m], B1[nl][ks],
                                                             acc[m][nl], 0, 0, 0);
  }

#pragma unroll
  for (int nl = 0; nl < 2; ++nl) {
    float bias = bn1[cb + nl * 16 + row];
#pragma unroll
    for (int m = 0; m < 4; ++m)
#pragma unroll
      for (int r = 0; r < 4; ++r)
        h1s[m * 16 + quad * 4 + r][cb + nl * 16 + row] =
            (short)f2bf(fmaxf(acc[m][nl][r] + bias, 0.0f));
  }

  bf16x8 B2[2][4], Bp[2][4];
#pragma unroll
  for (int nl = 0; nl < 2; ++nl)
#pragma unroll
    for (int ks = 0; ks < 4; ++ks) {
      B2[nl][ks] = *(const bf16x8*)(wn2 + (size_t)(cb + nl * 16 + row) * 128 +
                                    ks * 32 + quad * 8);
      Bp[nl][ks] = *(const bf16x8*)(wp + (size_t)(cb + nl * 16 + row) * 128 +
                                    ks * 32 + quad * 8);
    }
  __syncthreads();

  floatx4 acc2[4][2];
#pragma unroll
  for (int m = 0; m < 4; ++m)
#pragma unroll
    for (int nl = 0; nl < 2; ++nl) acc2[m][nl] = (floatx4){0.f, 0.f, 0.f, 0.f};

#pragma unroll
  for (int ks = 0; ks < 4; ++ks) {
    bf16x8 at[4], ax[4];
#pragma unroll
    for (int m = 0; m < 4; ++m) {
      at[m] = *(const bf16x8*)&h1s[m * 16 + row][ks * 32 + quad * 8];
      int n = n0 + m * 16 + row;
      ax[m] = *(const bf16x8*)(xh_bf + (size_t)n * 128 + ks * 32 + quad * 8);
    }
#pragma unroll
    for (int m = 0; m < 4; ++m)
#pragma unroll
      for (int nl = 0; nl < 2; ++nl) {
        acc2[m][nl] = __builtin_amdgcn_mfma_f32_16x16x32_bf16(at[m], B2[nl][ks],
                                                              acc2[m][nl], 0, 0, 0);
        acc2[m][nl] = __builtin_amdgcn_mfma_f32_16x16x32_bf16(ax[m], Bp[nl][ks],
                                                              acc2[m][nl], 0, 0, 0);
      }
  }

  // z = relu(acc2 + biases); LN partials: quad-shuffle over 32 owned cols
  float z[4][2][4];
#pragma unroll
  for (int m = 0; m < 4; ++m) {
    float s[4], ss[4];
#pragma unroll
    for (int r = 0; r < 4; ++r) { s[r] = 0.f; ss[r] = 0.f; }
#pragma unroll
    for (int nl = 0; nl < 2; ++nl) {
      float bias = bp[cb + nl * 16 + row] + bn2[cb + nl * 16 + row];
#pragma unroll
      for (int r = 0; r < 4; ++r) {
        float v = fmaxf(acc2[m][nl][r] + bias, 0.0f);
        z[m][nl][r] = v;
        s[r] += v;
        ss[r] += v * v;
      }
    }
#pragma unroll
    for (int r = 0; r < 4; ++r) {
#pragma unroll
      for (int msk = 1; msk < 16; msk <<= 1) {
        s[r]  += __shfl_xor(s[r],  msk, 64);
        ss[r] += __shfl_xor(ss[r], msk, 64);
      }
      if (row == 0) part[m * 16 + quad * 4 + r][wave] = make_float2(s[r], ss[r]);
    }
  }
  __syncthreads();

#pragma unroll
  for (int m = 0; m < 4; ++m)
#pragma unroll
    for (int r = 0; r < 4; ++r) {
      int rr = m * 16 + quad * 4 + r;
      float2 p0 = part[rr][0], p1 = part[rr][1], p2 = part[rr][2], p3 = part[rr][3];
      float mean = (p0.x + p1.x + p2.x + p3.x) * (1.0f / 128.0f);
      float var  = (p0.y + p1.y + p2.y + p3.y) * (1.0f / 128.0f) - mean * mean;
      float rstd = rsqrtf(var + LN_EPS);
      int n = n0 + rr;
      if (n < H_N) {
#pragma unroll
        for (int nl = 0; nl < 2; ++nl) {
          int col = cb + nl * 16 + row;
          out[(size_t)n * 128 + col] =
              (z[m][nl][r] - mean) * rstd * gamma[col] + beta[col];
        }
      }
    }
}

// ---------------------------------------------------------------------------
extern "C" void kernel_launch(void* const* d_in, const int* in_sizes, int n_in,
                              void* d_out, int out_size, void* d_ws, size_t ws_size,
                              hipStream_t stream) {
  const float* x_h   = (const float*)d_in[0];
  const float* attr  = (const float*)d_in[1];
  const float* Wp    = (const float*)d_in[2];
  const float* bp    = (const float*)d_in[3];
  const float* We1   = (const float*)d_in[4];
  const float* be1   = (const float*)d_in[5];
  const float* We2   = (const float*)d_in[6];
  const float* be2   = (const float*)d_in[7];
  const float* Wn1   = (const float*)d_in[8];
  const float* bn1   = (const float*)d_in[9];
  const float* Wn2   = (const float*)d_in[10];
  const float* bn2   = (const float*)d_in[11];
  const float* gamma = (const float*)d_in[12];
  const float* beta  = (const float*)d_in[13];
  const int*   fg    = (const int*)d_in[14];
  const int*   res   = (const int*)d_in[15];
  float* out = (float*)d_out;

  // ---- workspace layout ----
  int* cur_e  = (int*)d_ws;                 // E
  int* cur_h  = cur_e + E_N;                // H
  int* off_e  = cur_h + H_N;                // E+1
  int* off_h  = off_e + E_N + 1;            // H+1
  int* bsum_e = off_h + H_N + 1;            // 128
  int* bsum_h = bsum_e + 128;               // 128
  int* perm_e = bsum_h + 128;               // NI
  int* perm_h = perm_e + NI_N;              // NI
  uintptr_t pa = ((uintptr_t)(perm_h + NI_N) + 63) & ~(uintptr_t)63;
  unsigned short* xh_bf     = (unsigned short*)pa;          // H*128 bf16
  unsigned short* edge_mean = xh_bf + (size_t)H_N * 128;    // E*128 bf16
  unsigned short* edge_msg  = edge_mean + (size_t)E_N * 128;// E*128 bf16
  unsigned short* node_msg  = edge_msg + (size_t)E_N * 128; // H*128 bf16
  short* w1  = (short*)(node_msg + (size_t)H_N * 128);      // 128*192
  short* w2  = w1 + 128 * 192;
  short* wn1 = w2 + 128 * 128;
  short* wn2 = wn1 + 128 * 128;
  short* wp  = wn2 + 128 * 128;

  const int nb_e = (E_N + 2047) / 2048;
  const int nb_h = (H_N + 2047) / 2048;

  hipMemsetAsync(cur_e, 0, (size_t)(E_N + H_N) * 4, stream);

  {
    int n4 = H_N * 128 / 4;
    k_cvt_bf16<<<(n4 + 255) / 256, 256, 0, stream>>>((const float4*)x_h, xh_bf, n4);
    n4 = 128 * 192 / 4;
    k_cvt_bf16<<<(n4 + 255) / 256, 256, 0, stream>>>((const float4*)We1, (unsigned short*)w1, n4);
    n4 = 128 * 128 / 4;
    k_cvt_bf16<<<(n4 + 255) / 256, 256, 0, stream>>>((const float4*)We2, (unsigned short*)w2, n4);
    k_cvt_bf16<<<(n4 + 255) / 256, 256, 0, stream>>>((const float4*)Wn1, (unsigned short*)wn1, n4);
    k_cvt_bf16<<<(n4 + 255) / 256, 256, 0, stream>>>((const float4*)Wn2, (unsigned short*)wn2, n4);
    k_cvt_bf16<<<(n4 + 255) / 256, 256, 0, stream>>>((const float4*)Wp, (unsigned short*)wp, n4);
  }

  k_hist<<<(NI_N + 255) / 256, 256, 0, stream>>>(fg, res, cur_h, cur_e);
  k_scan1<<<nb_e, 256, 0, stream>>>(cur_e, off_e, bsum_e, E_N);
  k_scan1<<<nb_h, 256, 0, stream>>>(cur_h, off_h, bsum_h, H_N);
  k_scan2<<<1, 128, 0, stream>>>(bsum_e, nb_e);
  k_scan2<<<1, 128, 0, stream>>>(bsum_h, nb_h);
  k_scan3<<<nb_e, 256, 0, stream>>>(off_e, bsum_e, E_N, NI_N);
  k_scan3<<<nb_h, 256, 0, stream>>>(off_h, bsum_h, H_N, NI_N);
  hipMemsetAsync(cur_e, 0, (size_t)(E_N + H_N) * 4, stream);
  k_perm<<<(NI_N + 255) / 256, 256, 0, stream>>>(fg, res, off_e, off_h,
                                                 cur_e, cur_h, perm_e, perm_h);

  k_gather_mean<<<(E_N + 3) / 4, 256, 0, stream>>>(xh_bf, perm_e, off_e,
                                                   edge_mean, E_N);
  k_edge_mlp<<<E_N / 64, 256, 0, stream>>>((const short*)edge_mean, attr,
                                           w1, be1, w2, be2, edge_msg);
  k_gather_mean<<<(H_N + 3) / 4, 256, 0, stream>>>(edge_msg, perm_h, off_h,
                                                   node_msg, H_N);
  k_node_mlp_ln<<<(H_N + 63) / 64, 256, 0, stream>>>((const short*)node_msg,
                                                     (const short*)xh_bf,
                                                     wp, bp, wn1, bn1, wn2, bn2,
                                                     gamma, beta, out);
}

// Round 5
// 655.031 us; speedup vs baseline: 7.7287x; 1.0697x over previous
//
#include <hip/hip_runtime.h>

#define H_N   100000
#define E_N   200000
#define NI_N  1000000
#define LN_EPS 1e-5f

#define NBUCK  1563        // ceil(200000/128) == ceil(100000/64)
#define SEGB_E 128
#define SEGB_H 64
#define CAP    832         // bucket capacity; mean 640, sigma ~25 -> +7.6 sigma

typedef __attribute__((ext_vector_type(8))) short bf16x8;
typedef __attribute__((ext_vector_type(4))) float floatx4;

__device__ inline unsigned short f2bf(float f) {
  unsigned u = __builtin_bit_cast(unsigned, f);
  u += 0x7fffu + ((u >> 16) & 1u);           // round-to-nearest-even
  return (unsigned short)(u >> 16);
}
__device__ inline float bf2f(unsigned short s) {
  unsigned u = ((unsigned)s) << 16;
  return __builtin_bit_cast(float, u);
}

// ---------------------------------------------------------------------------
// fp32 -> bf16 conversion, 4 elements/thread
// ---------------------------------------------------------------------------
__global__ __launch_bounds__(256) void k_cvt_bf16(const float4* __restrict__ src,
                                                  unsigned short* __restrict__ dst,
                                                  int n4) {
  int i = blockIdx.x * 256 + threadIdx.x;
  if (i >= n4) return;
  float4 v = src[i];
  union { unsigned short us[4]; unsigned long long u64; } p;
  p.us[0] = f2bf(v.x); p.us[1] = f2bf(v.y);
  p.us[2] = f2bf(v.z); p.us[3] = f2bf(v.w);
  *(unsigned long long*)(dst + (size_t)i * 4) = p.u64;
}

// ---------------------------------------------------------------------------
// Bucket binning: one pass over incidences, packed 32-bit pairs into
// fixed-stride bucket regions. seg_local in bits [24..31), payload < 2^18.
// ---------------------------------------------------------------------------
__global__ __launch_bounds__(256) void k_bucket(
    const int* __restrict__ fg, const int* __restrict__ res,
    int* __restrict__ bcnt_e, int* __restrict__ bcnt_h,
    unsigned* __restrict__ pairs_e, unsigned* __restrict__ pairs_h) {
  int i = blockIdx.x * 256 + threadIdx.x;
  if (i >= NI_N) return;
  int f = fg[i], r = res[i];
  int be = r >> 7, se = r & 127;
  int pe = atomicAdd(bcnt_e + be, 1);
  if (pe < CAP) pairs_e[(size_t)be * CAP + pe] = ((unsigned)se << 24) | (unsigned)f;
  int bh = f >> 6, sh = f & 63;
  int ph = atomicAdd(bcnt_h + bh, 1);
  if (ph < CAP) pairs_h[(size_t)bh * CAP + ph] = ((unsigned)sh << 24) | (unsigned)r;
}

// ---------------------------------------------------------------------------
// Per-bucket: LDS counting sort by seg_local, then gather-mean.
// One block per bucket; wave per segment round-robin; 2 bf16 cols/lane.
// ---------------------------------------------------------------------------
__global__ __launch_bounds__(256) void k_seg_mean(
    const unsigned short* __restrict__ rows, const unsigned* __restrict__ pairs,
    const int* __restrict__ bcnt, unsigned short* __restrict__ outm,
    int nseg, int segb) {
  __shared__ unsigned raw[CAP];
  __shared__ unsigned sortedp[CAP];
  __shared__ int cnts[129];      // exclusive offsets after scan
  __shared__ int curs[128];
  const int b = blockIdx.x;
  const int t = threadIdx.x;
  const int cnt = min(bcnt[b], CAP);

  for (int j = t; j < cnt; j += 256) raw[j] = pairs[(size_t)b * CAP + j];
  if (t <= segb) cnts[t] = 0;
  __syncthreads();
  for (int j = t; j < cnt; j += 256)
    atomicAdd(&cnts[(raw[j] >> 24) + 1], 1);
  __syncthreads();
  // inclusive scan over cnts[0..segb] (cnts[0]=0) -> cnts[s] = seg s offset
  for (int d = 1; d <= segb; d <<= 1) {
    int v = 0;
    if (t <= segb && t >= d) v = cnts[t - d];
    __syncthreads();
    if (t <= segb) cnts[t] += v;
    __syncthreads();
  }
  if (t < segb) curs[t] = cnts[t];
  __syncthreads();
  for (int j = t; j < cnt; j += 256) {
    unsigned p = raw[j];
    int s = p >> 24;
    int d = atomicAdd(&curs[s], 1);
    sortedp[d] = p & 0xFFFFFFu;
  }
  __syncthreads();

  const int wave = t >> 6, lane = t & 63;
  const int segs_here = min(segb, nseg - b * segb);
  for (int s = wave; s < segs_here; s += 4) {
    int o = cnts[s], e = cnts[s + 1];
    float a0 = 0.f, a1 = 0.f;
    int j = o;
    for (; j + 1 < e; j += 2) {
      int i0 = sortedp[j], i1 = sortedp[j + 1];
      unsigned v0 = *(const unsigned*)(rows + (size_t)i0 * 128 + lane * 2);
      unsigned v1 = *(const unsigned*)(rows + (size_t)i1 * 128 + lane * 2);
      a0 += bf2f((unsigned short)(v0 & 0xffffu)) + bf2f((unsigned short)(v1 & 0xffffu));
      a1 += bf2f((unsigned short)(v0 >> 16)) + bf2f((unsigned short)(v1 >> 16));
    }
    if (j < e) {
      int i0 = sortedp[j];
      unsigned v0 = *(const unsigned*)(rows + (size_t)i0 * 128 + lane * 2);
      a0 += bf2f((unsigned short)(v0 & 0xffffu));
      a1 += bf2f((unsigned short)(v0 >> 16));
    }
    float inv = (e > o) ? 1.0f / (float)(e - o) : 0.0f;
    unsigned ov = (unsigned)f2bf(a0 * inv) | ((unsigned)f2bf(a1 * inv) << 16);
    *(unsigned*)(outm + (size_t)(b * segb + s) * 128 + lane * 2) = ov;
  }
}

// ---------------------------------------------------------------------------
// Edge MLP, N-split: block = 64 edges, each wave owns 32 output cols.
// ---------------------------------------------------------------------------
__global__ __launch_bounds__(256) void k_edge_mlp(
    const short* __restrict__ edge_mean, const float* __restrict__ attr,
    const short* __restrict__ w1, const float* __restrict__ b1,
    const short* __restrict__ w2, const float* __restrict__ b2,
    unsigned short* __restrict__ edge_msg) {
  __shared__ short h1s[64][136];
  const int wave = threadIdx.x >> 6;
  const int lane = threadIdx.x & 63;
  const int row  = lane & 15;
  const int quad = lane >> 4;
  const int e0   = blockIdx.x * 64;
  const int cb   = wave * 32;

  bf16x8 B1[2][6];
#pragma unroll
  for (int nl = 0; nl < 2; ++nl)
#pragma unroll
    for (int ks = 0; ks < 6; ++ks)
      B1[nl][ks] = *(const bf16x8*)(w1 + (size_t)(cb + nl * 16 + row) * 192 +
                                    ks * 32 + quad * 8);

  floatx4 acc[4][2];
#pragma unroll
  for (int m = 0; m < 4; ++m)
#pragma unroll
    for (int nl = 0; nl < 2; ++nl) acc[m][nl] = (floatx4){0.f, 0.f, 0.f, 0.f};

#pragma unroll
  for (int ks = 0; ks < 6; ++ks) {
    bf16x8 a[4];
#pragma unroll
    for (int m = 0; m < 4; ++m) {
      int e = e0 + m * 16 + row;
      if (ks < 4) {
        a[m] = *(const bf16x8*)(edge_mean + (size_t)e * 128 + ks * 32 + quad * 8);
      } else {
        const float4* p = (const float4*)(attr + (size_t)e * 64 +
                                          (ks - 4) * 32 + quad * 8);
        float4 u0 = p[0], u1 = p[1];
        a[m][0] = (short)f2bf(u0.x); a[m][1] = (short)f2bf(u0.y);
        a[m][2] = (short)f2bf(u0.z); a[m][3] = (short)f2bf(u0.w);
        a[m][4] = (short)f2bf(u1.x); a[m][5] = (short)f2bf(u1.y);
        a[m][6] = (short)f2bf(u1.z); a[m][7] = (short)f2bf(u1.w);
      }
    }
#pragma unroll
    for (int m = 0; m < 4; ++m)
#pragma unroll
      for (int nl = 0; nl < 2; ++nl)
        acc[m][nl] = __builtin_amdgcn_mfma_f32_16x16x32_bf16(a[m], B1[nl][ks],
                                                             acc[m][nl], 0, 0, 0);
  }

#pragma unroll
  for (int nl = 0; nl < 2; ++nl) {
    float bias = b1[cb + nl * 16 + row];
#pragma unroll
    for (int m = 0; m < 4; ++m)
#pragma unroll
      for (int r = 0; r < 4; ++r)
        h1s[m * 16 + quad * 4 + r][cb + nl * 16 + row] =
            (short)f2bf(fmaxf(acc[m][nl][r] + bias, 0.0f));
  }

  bf16x8 B2[2][4];
#pragma unroll
  for (int nl = 0; nl < 2; ++nl)
#pragma unroll
    for (int ks = 0; ks < 4; ++ks)
      B2[nl][ks] = *(const bf16x8*)(w2 + (size_t)(cb + nl * 16 + row) * 128 +
                                    ks * 32 + quad * 8);
  __syncthreads();

  floatx4 acc2[4][2];
#pragma unroll
  for (int m = 0; m < 4; ++m)
#pragma unroll
    for (int nl = 0; nl < 2; ++nl) acc2[m][nl] = (floatx4){0.f, 0.f, 0.f, 0.f};

#pragma unroll
  for (int ks = 0; ks < 4; ++ks) {
    bf16x8 a[4];
#pragma unroll
    for (int m = 0; m < 4; ++m)
      a[m] = *(const bf16x8*)&h1s[m * 16 + row][ks * 32 + quad * 8];
#pragma unroll
    for (int m = 0; m < 4; ++m)
#pragma unroll
      for (int nl = 0; nl < 2; ++nl)
        acc2[m][nl] = __builtin_amdgcn_mfma_f32_16x16x32_bf16(a[m], B2[nl][ks],
                                                              acc2[m][nl], 0, 0, 0);
  }

#pragma unroll
  for (int nl = 0; nl < 2; ++nl) {
    int col = cb + nl * 16 + row;
    float bias = b2[col];
#pragma unroll
    for (int m = 0; m < 4; ++m)
#pragma unroll
      for (int r = 0; r < 4; ++r)
        edge_msg[(size_t)(e0 + m * 16 + quad * 4 + r) * 128 + col] =
            f2bf(acc2[m][nl][r] + bias);
  }
}

// ---------------------------------------------------------------------------
// Node MLP + residual projection + relu + LayerNorm, N-split.
// ---------------------------------------------------------------------------
__global__ __launch_bounds__(256) void k_node_mlp_ln(
    const short* __restrict__ node_msg, const short* __restrict__ xh_bf,
    const short* __restrict__ wp, const float* __restrict__ bp,
    const short* __restrict__ wn1, const float* __restrict__ bn1,
    const short* __restrict__ wn2, const float* __restrict__ bn2,
    const float* __restrict__ gamma, const float* __restrict__ beta,
    float* __restrict__ out) {
  __shared__ short h1s[64][136];
  __shared__ float2 part[64][4];
  const int wave = threadIdx.x >> 6;
  const int lane = threadIdx.x & 63;
  const int row  = lane & 15;
  const int quad = lane >> 4;
  const int n0   = blockIdx.x * 64;
  const int cb   = wave * 32;

  bf16x8 B1[2][4];
#pragma unroll
  for (int nl = 0; nl < 2; ++nl)
#pragma unroll
    for (int ks = 0; ks < 4; ++ks)
      B1[nl][ks] = *(const bf16x8*)(wn1 + (size_t)(cb + nl * 16 + row) * 128 +
                                    ks * 32 + quad * 8);

  floatx4 acc[4][2];
#pragma unroll
  for (int m = 0; m < 4; ++m)
#pragma unroll
    for (int nl = 0; nl < 2; ++nl) acc[m][nl] = (floatx4){0.f, 0.f, 0.f, 0.f};

#pragma unroll
  for (int ks = 0; ks < 4; ++ks) {
    bf16x8 a[4];
#pragma unroll
    for (int m = 0; m < 4; ++m) {
      int n = n0 + m * 16 + row;
      a[m] = *(const bf16x8*)(node_msg + (size_t)n * 128 + ks * 32 + quad * 8);
    }
#pragma unroll
    for (int m = 0; m < 4; ++m)
#pragma unroll
      for (int nl = 0; nl < 2; ++nl)
        acc[m][nl] = __builtin_amdgcn_mfma_f32_16x16x32_bf16(a[m], B1[nl][ks],
                                                             acc[m][nl], 0, 0, 0);
  }

#pragma unroll
  for (int nl = 0; nl < 2; ++nl) {
    float bias = bn1[cb + nl * 16 + row];
#pragma unroll
    for (int m = 0; m < 4; ++m)
#pragma unroll
      for (int r = 0; r < 4; ++r)
        h1s[m * 16 + quad * 4 + r][cb + nl * 16 + row] =
            (short)f2bf(fmaxf(acc[m][nl][r] + bias, 0.0f));
  }

  bf16x8 B2[2][4], Bp[2][4];
#pragma unroll
  for (int nl = 0; nl < 2; ++nl)
#pragma unroll
    for (int ks = 0; ks < 4; ++ks) {
      B2[nl][ks] = *(const bf16x8*)(wn2 + (size_t)(cb + nl * 16 + row) * 128 +
                                    ks * 32 + quad * 8);
      Bp[nl][ks] = *(const bf16x8*)(wp + (size_t)(cb + nl * 16 + row) * 128 +
                                    ks * 32 + quad * 8);
    }
  __syncthreads();

  floatx4 acc2[4][2];
#pragma unroll
  for (int m = 0; m < 4; ++m)
#pragma unroll
    for (int nl = 0; nl < 2; ++nl) acc2[m][nl] = (floatx4){0.f, 0.f, 0.f, 0.f};

#pragma unroll
  for (int ks = 0; ks < 4; ++ks) {
    bf16x8 at[4], ax[4];
#pragma unroll
    for (int m = 0; m < 4; ++m) {
      at[m] = *(const bf16x8*)&h1s[m * 16 + row][ks * 32 + quad * 8];
      int n = n0 + m * 16 + row;
      ax[m] = *(const bf16x8*)(xh_bf + (size_t)n * 128 + ks * 32 + quad * 8);
    }
#pragma unroll
    for (int m = 0; m < 4; ++m)
#pragma unroll
      for (int nl = 0; nl < 2; ++nl) {
        acc2[m][nl] = __builtin_amdgcn_mfma_f32_16x16x32_bf16(at[m], B2[nl][ks],
                                                              acc2[m][nl], 0, 0, 0);
        acc2[m][nl] = __builtin_amdgcn_mfma_f32_16x16x32_bf16(ax[m], Bp[nl][ks],
                                                              acc2[m][nl], 0, 0, 0);
      }
  }

  float z[4][2][4];
#pragma unroll
  for (int m = 0; m < 4; ++m) {
    float s[4], ss[4];
#pragma unroll
    for (int r = 0; r < 4; ++r) { s[r] = 0.f; ss[r] = 0.f; }
#pragma unroll
    for (int nl = 0; nl < 2; ++nl) {
      float bias = bp[cb + nl * 16 + row] + bn2[cb + nl * 16 + row];
#pragma unroll
      for (int r = 0; r < 4; ++r) {
        float v = fmaxf(acc2[m][nl][r] + bias, 0.0f);
        z[m][nl][r] = v;
        s[r] += v;
        ss[r] += v * v;
      }
    }
#pragma unroll
    for (int r = 0; r < 4; ++r) {
#pragma unroll
      for (int msk = 1; msk < 16; msk <<= 1) {
        s[r]  += __shfl_xor(s[r],  msk, 64);
        ss[r] += __shfl_xor(ss[r], msk, 64);
      }
      if (row == 0) part[m * 16 + quad * 4 + r][wave] = make_float2(s[r], ss[r]);
    }
  }
  __syncthreads();

#pragma unroll
  for (int m = 0; m < 4; ++m)
#pragma unroll
    for (int r = 0; r < 4; ++r) {
      int rr = m * 16 + quad * 4 + r;
      float2 p0 = part[rr][0], p1 = part[rr][1], p2 = part[rr][2], p3 = part[rr][3];
      float mean = (p0.x + p1.x + p2.x + p3.x) * (1.0f / 128.0f);
      float var  = (p0.y + p1.y + p2.y + p3.y) * (1.0f / 128.0f) - mean * mean;
      float rstd = rsqrtf(var + LN_EPS);
      int n = n0 + rr;
      if (n < H_N) {
#pragma unroll
        for (int nl = 0; nl < 2; ++nl) {
          int col = cb + nl * 16 + row;
          out[(size_t)n * 128 + col] =
              (z[m][nl][r] - mean) * rstd * gamma[col] + beta[col];
        }
      }
    }
}

// ---------------------------------------------------------------------------
extern "C" void kernel_launch(void* const* d_in, const int* in_sizes, int n_in,
                              void* d_out, int out_size, void* d_ws, size_t ws_size,
                              hipStream_t stream) {
  const float* x_h   = (const float*)d_in[0];
  const float* attr  = (const float*)d_in[1];
  const float* Wp    = (const float*)d_in[2];
  const float* bp    = (const float*)d_in[3];
  const float* We1   = (const float*)d_in[4];
  const float* be1   = (const float*)d_in[5];
  const float* We2   = (const float*)d_in[6];
  const float* be2   = (const float*)d_in[7];
  const float* Wn1   = (const float*)d_in[8];
  const float* bn1   = (const float*)d_in[9];
  const float* Wn2   = (const float*)d_in[10];
  const float* bn2   = (const float*)d_in[11];
  const float* gamma = (const float*)d_in[12];
  const float* beta  = (const float*)d_in[13];
  const int*   fg    = (const int*)d_in[14];
  const int*   res   = (const int*)d_in[15];
  float* out = (float*)d_out;

  // ---- workspace layout ----
  int* bcnt_e = (int*)d_ws;                         // NBUCK
  int* bcnt_h = bcnt_e + NBUCK;                     // NBUCK
  unsigned* pairs_e = (unsigned*)(bcnt_h + NBUCK);  // NBUCK*CAP
  unsigned* pairs_h = pairs_e + (size_t)NBUCK * CAP;
  unsigned short* xh_bf     = (unsigned short*)(pairs_h + (size_t)NBUCK * CAP);
  unsigned short* edge_mean = xh_bf + (size_t)H_N * 128;
  unsigned short* edge_msg  = edge_mean + (size_t)E_N * 128;
  unsigned short* node_msg  = edge_msg + (size_t)E_N * 128;
  short* w1  = (short*)(node_msg + (size_t)H_N * 128);
  short* w2  = w1 + 128 * 192;
  short* wn1 = w2 + 128 * 128;
  short* wn2 = wn1 + 128 * 128;
  short* wp  = wn2 + 128 * 128;

  hipMemsetAsync(bcnt_e, 0, (size_t)2 * NBUCK * 4, stream);

  {
    int n4 = H_N * 128 / 4;
    k_cvt_bf16<<<(n4 + 255) / 256, 256, 0, stream>>>((const float4*)x_h, xh_bf, n4);
    n4 = 128 * 192 / 4;
    k_cvt_bf16<<<(n4 + 255) / 256, 256, 0, stream>>>((const float4*)We1, (unsigned short*)w1, n4);
    n4 = 128 * 128 / 4;
    k_cvt_bf16<<<(n4 + 255) / 256, 256, 0, stream>>>((const float4*)We2, (unsigned short*)w2, n4);
    k_cvt_bf16<<<(n4 + 255) / 256, 256, 0, stream>>>((const float4*)Wn1, (unsigned short*)wn1, n4);
    k_cvt_bf16<<<(n4 + 255) / 256, 256, 0, stream>>>((const float4*)Wn2, (unsigned short*)wn2, n4);
    k_cvt_bf16<<<(n4 + 255) / 256, 256, 0, stream>>>((const float4*)Wp, (unsigned short*)wp, n4);
  }

  k_bucket<<<(NI_N + 255) / 256, 256, 0, stream>>>(fg, res, bcnt_e, bcnt_h,
                                                   pairs_e, pairs_h);

  k_seg_mean<<<NBUCK, 256, 0, stream>>>(xh_bf, pairs_e, bcnt_e,
                                        edge_mean, E_N, SEGB_E);
  k_edge_mlp<<<E_N / 64, 256, 0, stream>>>((const short*)edge_mean, attr,
                                           w1, be1, w2, be2, edge_msg);
  k_seg_mean<<<NBUCK, 256, 0, stream>>>(edge_msg, pairs_h, bcnt_h,
                                        node_msg, H_N, SEGB_H);
  k_node_mlp_ln<<<(H_N + 63) / 64, 256, 0, stream>>>((const short*)node_msg,
                                                     (const short*)xh_bf,
                                                     wp, bp, wn1, bn1, wn2, bn2,
                                                     gamma, beta, out);
}

// Round 6
// 527.734 us; speedup vs baseline: 9.5930x; 1.2412x over previous
//
#include <hip/hip_runtime.h>

#define H_N   100000
#define E_N   200000
#define NI_N  1000000
#define LN_EPS 1e-5f

#define NBUCK  1563        // ceil(200000/128) == ceil(100000/64)
#define SEGB_E 128
#define SEGB_H 64
#define CAP    1024        // total per-bucket capacity (mean 640, sigma ~25)
#define SUBCAP 192         // per-XCD sub-bucket capacity (mean 80, sigma ~9)

typedef __attribute__((ext_vector_type(8))) short bf16x8;
typedef __attribute__((ext_vector_type(4))) float floatx4;

__device__ inline unsigned short f2bf(float f) {
  unsigned u = __builtin_bit_cast(unsigned, f);
  u += 0x7fffu + ((u >> 16) & 1u);           // round-to-nearest-even
  return (unsigned short)(u >> 16);
}
__device__ inline float bf2f(unsigned short s) {
  unsigned u = ((unsigned)s) << 16;
  return __builtin_bit_cast(float, u);
}
__device__ inline unsigned get_xcc() {
  unsigned x;
  asm volatile("s_getreg_b32 %0, hwreg(HW_REG_XCC_ID)" : "=s"(x));
  return x & 7;
}

// ---------------------------------------------------------------------------
// fp32 -> bf16 conversion, 4 elements/thread
// ---------------------------------------------------------------------------
__global__ __launch_bounds__(256) void k_cvt_bf16(const float4* __restrict__ src,
                                                  unsigned short* __restrict__ dst,
                                                  int n4) {
  int i = blockIdx.x * 256 + threadIdx.x;
  if (i >= n4) return;
  float4 v = src[i];
  union { unsigned short us[4]; unsigned long long u64; } p;
  p.us[0] = f2bf(v.x); p.us[1] = f2bf(v.y);
  p.us[2] = f2bf(v.z); p.us[3] = f2bf(v.w);
  *(unsigned long long*)(dst + (size_t)i * 4) = p.u64;
}

// ---------------------------------------------------------------------------
// Bucket binning, XCD-local: each bucket has 8 per-XCD sub-regions so all
// writes to a sub-region stay within one XCD's L2 (lines fill -> ~1x
// writeback). Layout: pairs[((xcc*NBUCK)+bucket)*SUBCAP + slot].
// ---------------------------------------------------------------------------
__global__ __launch_bounds__(256) void k_bucket(
    const int* __restrict__ fg, const int* __restrict__ res,
    int* __restrict__ bcnt_e, int* __restrict__ bcnt_h,
    unsigned* __restrict__ pairs_e, unsigned* __restrict__ pairs_h) {
  int i = blockIdx.x * 256 + threadIdx.x;
  if (i >= NI_N) return;
  unsigned xcc = get_xcc();
  int f = fg[i], r = res[i];
  int be = r >> 7, se = r & 127;
  int pe = atomicAdd(bcnt_e + xcc * NBUCK + be, 1);
  if (pe < SUBCAP)
    pairs_e[((size_t)xcc * NBUCK + be) * SUBCAP + pe] =
        ((unsigned)se << 24) | (unsigned)f;
  int bh = f >> 6, sh = f & 63;
  int ph = atomicAdd(bcnt_h + xcc * NBUCK + bh, 1);
  if (ph < SUBCAP)
    pairs_h[((size_t)xcc * NBUCK + bh) * SUBCAP + ph] =
        ((unsigned)sh << 24) | (unsigned)r;
}

// ---------------------------------------------------------------------------
// Per-bucket: concat 8 sub-lists -> LDS counting sort -> gather-mean.
// ---------------------------------------------------------------------------
__global__ __launch_bounds__(256) void k_seg_mean(
    const unsigned short* __restrict__ rows, const unsigned* __restrict__ pairs,
    const int* __restrict__ bcnt, unsigned short* __restrict__ outm,
    int nseg, int segb) {
  __shared__ unsigned raw[CAP];
  __shared__ unsigned sortedp[CAP];
  __shared__ int cnts[129];
  __shared__ int curs[128];
  const int b = blockIdx.x;
  const int t = threadIdx.x;

  int total = 0;
#pragma unroll
  for (int x = 0; x < 8; ++x) {
    int c = min(bcnt[x * NBUCK + b], SUBCAP);
    const unsigned* src = pairs + ((size_t)x * NBUCK + b) * SUBCAP;
    for (int j = t; j < c; j += 256) {
      int d = total + j;
      if (d < CAP) raw[d] = src[j];
    }
    total += c;
  }
  const int cnt = min(total, CAP);
  if (t <= segb) cnts[t] = 0;
  __syncthreads();
  for (int j = t; j < cnt; j += 256)
    atomicAdd(&cnts[(raw[j] >> 24) + 1], 1);
  __syncthreads();
  for (int d = 1; d <= segb; d <<= 1) {
    int v = 0;
    if (t <= segb && t >= d) v = cnts[t - d];
    __syncthreads();
    if (t <= segb) cnts[t] += v;
    __syncthreads();
  }
  if (t < segb) curs[t] = cnts[t];
  __syncthreads();
  for (int j = t; j < cnt; j += 256) {
    unsigned p = raw[j];
    int s = p >> 24;
    int d = atomicAdd(&curs[s], 1);
    sortedp[d] = p & 0xFFFFFFu;
  }
  __syncthreads();

  const int wave = t >> 6, lane = t & 63;
  const int segs_here = min(segb, nseg - b * segb);
  for (int s = wave; s < segs_here; s += 4) {
    int o = cnts[s], e = cnts[s + 1];
    float a0 = 0.f, a1 = 0.f;
    int j = o;
    for (; j + 1 < e; j += 2) {
      int i0 = sortedp[j], i1 = sortedp[j + 1];
      unsigned v0 = *(const unsigned*)(rows + (size_t)i0 * 128 + lane * 2);
      unsigned v1 = *(const unsigned*)(rows + (size_t)i1 * 128 + lane * 2);
      a0 += bf2f((unsigned short)(v0 & 0xffffu)) + bf2f((unsigned short)(v1 & 0xffffu));
      a1 += bf2f((unsigned short)(v0 >> 16)) + bf2f((unsigned short)(v1 >> 16));
    }
    if (j < e) {
      int i0 = sortedp[j];
      unsigned v0 = *(const unsigned*)(rows + (size_t)i0 * 128 + lane * 2);
      a0 += bf2f((unsigned short)(v0 & 0xffffu));
      a1 += bf2f((unsigned short)(v0 >> 16));
    }
    float inv = (e > o) ? 1.0f / (float)(e - o) : 0.0f;
    unsigned ov = (unsigned)f2bf(a0 * inv) | ((unsigned)f2bf(a1 * inv) << 16);
    *(unsigned*)(outm + (size_t)(b * segb + s) * 128 + lane * 2) = ov;
  }
}

// ---------------------------------------------------------------------------
// Edge MLP, N-split: block = 64 edges, each wave owns 32 output cols.
// ---------------------------------------------------------------------------
__global__ __launch_bounds__(256) void k_edge_mlp(
    const short* __restrict__ edge_mean, const float* __restrict__ attr,
    const short* __restrict__ w1, const float* __restrict__ b1,
    const short* __restrict__ w2, const float* __restrict__ b2,
    unsigned short* __restrict__ edge_msg) {
  __shared__ short h1s[64][136];
  const int wave = threadIdx.x >> 6;
  const int lane = threadIdx.x & 63;
  const int row  = lane & 15;
  const int quad = lane >> 4;
  const int e0   = blockIdx.x * 64;
  const int cb   = wave * 32;

  bf16x8 B1[2][6];
#pragma unroll
  for (int nl = 0; nl < 2; ++nl)
#pragma unroll
    for (int ks = 0; ks < 6; ++ks)
      B1[nl][ks] = *(const bf16x8*)(w1 + (size_t)(cb + nl * 16 + row) * 192 +
                                    ks * 32 + quad * 8);

  floatx4 acc[4][2];
#pragma unroll
  for (int m = 0; m < 4; ++m)
#pragma unroll
    for (int nl = 0; nl < 2; ++nl) acc[m][nl] = (floatx4){0.f, 0.f, 0.f, 0.f};

#pragma unroll
  for (int ks = 0; ks < 6; ++ks) {
    bf16x8 a[4];
#pragma unroll
    for (int m = 0; m < 4; ++m) {
      int e = e0 + m * 16 + row;
      if (ks < 4) {
        a[m] = *(const bf16x8*)(edge_mean + (size_t)e * 128 + ks * 32 + quad * 8);
      } else {
        const float4* p = (const float4*)(attr + (size_t)e * 64 +
                                          (ks - 4) * 32 + quad * 8);
        float4 u0 = p[0], u1 = p[1];
        a[m][0] = (short)f2bf(u0.x); a[m][1] = (short)f2bf(u0.y);
        a[m][2] = (short)f2bf(u0.z); a[m][3] = (short)f2bf(u0.w);
        a[m][4] = (short)f2bf(u1.x); a[m][5] = (short)f2bf(u1.y);
        a[m][6] = (short)f2bf(u1.z); a[m][7] = (short)f2bf(u1.w);
      }
    }
#pragma unroll
    for (int m = 0; m < 4; ++m)
#pragma unroll
      for (int nl = 0; nl < 2; ++nl)
        acc[m][nl] = __builtin_amdgcn_mfma_f32_16x16x32_bf16(a[m], B1[nl][ks],
                                                             acc[m][nl], 0, 0, 0);
  }

#pragma unroll
  for (int nl = 0; nl < 2; ++nl) {
    float bias = b1[cb + nl * 16 + row];
#pragma unroll
    for (int m = 0; m < 4; ++m)
#pragma unroll
      for (int r = 0; r < 4; ++r)
        h1s[m * 16 + quad * 4 + r][cb + nl * 16 + row] =
            (short)f2bf(fmaxf(acc[m][nl][r] + bias, 0.0f));
  }

  bf16x8 B2[2][4];
#pragma unroll
  for (int nl = 0; nl < 2; ++nl)
#pragma unroll
    for (int ks = 0; ks < 4; ++ks)
      B2[nl][ks] = *(const bf16x8*)(w2 + (size_t)(cb + nl * 16 + row) * 128 +
                                    ks * 32 + quad * 8);
  __syncthreads();

  floatx4 acc2[4][2];
#pragma unroll
  for (int m = 0; m < 4; ++m)
#pragma unroll
    for (int nl = 0; nl < 2; ++nl) acc2[m][nl] = (floatx4){0.f, 0.f, 0.f, 0.f};

#pragma unroll
  for (int ks = 0; ks < 4; ++ks) {
    bf16x8 a[4];
#pragma unroll
    for (int m = 0; m < 4; ++m)
      a[m] = *(const bf16x8*)&h1s[m * 16 + row][ks * 32 + quad * 8];
#pragma unroll
    for (int m = 0; m < 4; ++m)
#pragma unroll
      for (int nl = 0; nl < 2; ++nl)
        acc2[m][nl] = __builtin_amdgcn_mfma_f32_16x16x32_bf16(a[m], B2[nl][ks],
                                                              acc2[m][nl], 0, 0, 0);
  }

#pragma unroll
  for (int nl = 0; nl < 2; ++nl) {
    int col = cb + nl * 16 + row;
    float bias = b2[col];
#pragma unroll
    for (int m = 0; m < 4; ++m)
#pragma unroll
      for (int r = 0; r < 4; ++r)
        edge_msg[(size_t)(e0 + m * 16 + quad * 4 + r) * 128 + col] =
            f2bf(acc2[m][nl][r] + bias);
  }
}

// ---------------------------------------------------------------------------
// Node MLP + residual projection + relu + LayerNorm, N-split.
// ---------------------------------------------------------------------------
__global__ __launch_bounds__(256) void k_node_mlp_ln(
    const short* __restrict__ node_msg, const short* __restrict__ xh_bf,
    const short* __restrict__ wp, const float* __restrict__ bp,
    const short* __restrict__ wn1, const float* __restrict__ bn1,
    const short* __restrict__ wn2, const float* __restrict__ bn2,
    const float* __restrict__ gamma, const float* __restrict__ beta,
    float* __restrict__ out) {
  __shared__ short h1s[64][136];
  __shared__ float2 part[64][4];
  const int wave = threadIdx.x >> 6;
  const int lane = threadIdx.x & 63;
  const int row  = lane & 15;
  const int quad = lane >> 4;
  const int n0   = blockIdx.x * 64;
  const int cb   = wave * 32;

  bf16x8 B1[2][4];
#pragma unroll
  for (int nl = 0; nl < 2; ++nl)
#pragma unroll
    for (int ks = 0; ks < 4; ++ks)
      B1[nl][ks] = *(const bf16x8*)(wn1 + (size_t)(cb + nl * 16 + row) * 128 +
                                    ks * 32 + quad * 8);

  floatx4 acc[4][2];
#pragma unroll
  for (int m = 0; m < 4; ++m)
#pragma unroll
    for (int nl = 0; nl < 2; ++nl) acc[m][nl] = (floatx4){0.f, 0.f, 0.f, 0.f};

#pragma unroll
  for (int ks = 0; ks < 4; ++ks) {
    bf16x8 a[4];
#pragma unroll
    for (int m = 0; m < 4; ++m) {
      int n = n0 + m * 16 + row;
      a[m] = *(const bf16x8*)(node_msg + (size_t)n * 128 + ks * 32 + quad * 8);
    }
#pragma unroll
    for (int m = 0; m < 4; ++m)
#pragma unroll
      for (int nl = 0; nl < 2; ++nl)
        acc[m][nl] = __builtin_amdgcn_mfma_f32_16x16x32_bf16(a[m], B1[nl][ks],
                                                             acc[m][nl], 0, 0, 0);
  }

#pragma unroll
  for (int nl = 0; nl < 2; ++nl) {
    float bias = bn1[cb + nl * 16 + row];
#pragma unroll
    for (int m = 0; m < 4; ++m)
#pragma unroll
      for (int r = 0; r < 4; ++r)
        h1s[m * 16 + quad * 4 + r][cb + nl * 16 + row] =
            (short)f2bf(fmaxf(acc[m][nl][r] + bias, 0.0f));
  }

  bf16x8 B2[2][4], Bp[2][4];
#pragma unroll
  for (int nl = 0; nl < 2; ++nl)
#pragma unroll
    for (int ks = 0; ks < 4; ++ks) {
      B2[nl][ks] = *(const bf16x8*)(wn2 + (size_t)(cb + nl * 16 + row) * 128 +
                                    ks * 32 + quad * 8);
      Bp[nl][ks] = *(const bf16x8*)(wp + (size_t)(cb + nl * 16 + row) * 128 +
                                    ks * 32 + quad * 8);
    }
  __syncthreads();

  floatx4 acc2[4][2];
#pragma unroll
  for (int m = 0; m < 4; ++m)
#pragma unroll
    for (int nl = 0; nl < 2; ++nl) acc2[m][nl] = (floatx4){0.f, 0.f, 0.f, 0.f};

#pragma unroll
  for (int ks = 0; ks < 4; ++ks) {
    bf16x8 at[4], ax[4];
#pragma unroll
    for (int m = 0; m < 4; ++m) {
      at[m] = *(const bf16x8*)&h1s[m * 16 + row][ks * 32 + quad * 8];
      int n = n0 + m * 16 + row;
      ax[m] = *(const bf16x8*)(xh_bf + (size_t)n * 128 + ks * 32 + quad * 8);
    }
#pragma unroll
    for (int m = 0; m < 4; ++m)
#pragma unroll
      for (int nl = 0; nl < 2; ++nl) {
        acc2[m][nl] = __builtin_amdgcn_mfma_f32_16x16x32_bf16(at[m], B2[nl][ks],
                                                              acc2[m][nl], 0, 0, 0);
        acc2[m][nl] = __builtin_amdgcn_mfma_f32_16x16x32_bf16(ax[m], Bp[nl][ks],
                                                              acc2[m][nl], 0, 0, 0);
      }
  }

  float z[4][2][4];
#pragma unroll
  for (int m = 0; m < 4; ++m) {
    float s[4], ss[4];
#pragma unroll
    for (int r = 0; r < 4; ++r) { s[r] = 0.f; ss[r] = 0.f; }
#pragma unroll
    for (int nl = 0; nl < 2; ++nl) {
      float bias = bp[cb + nl * 16 + row] + bn2[cb + nl * 16 + row];
#pragma unroll
      for (int r = 0; r < 4; ++r) {
        float v = fmaxf(acc2[m][nl][r] + bias, 0.0f);
        z[m][nl][r] = v;
        s[r] += v;
        ss[r] += v * v;
      }
    }
#pragma unroll
    for (int r = 0; r < 4; ++r) {
#pragma unroll
      for (int msk = 1; msk < 16; msk <<= 1) {
        s[r]  += __shfl_xor(s[r],  msk, 64);
        ss[r] += __shfl_xor(ss[r], msk, 64);
      }
      if (row == 0) part[m * 16 + quad * 4 + r][wave] = make_float2(s[r], ss[r]);
    }
  }
  __syncthreads();

#pragma unroll
  for (int m = 0; m < 4; ++m)
#pragma unroll
    for (int r = 0; r < 4; ++r) {
      int rr = m * 16 + quad * 4 + r;
      float2 p0 = part[rr][0], p1 = part[rr][1], p2 = part[rr][2], p3 = part[rr][3];
      float mean = (p0.x + p1.x + p2.x + p3.x) * (1.0f / 128.0f);
      float var  = (p0.y + p1.y + p2.y + p3.y) * (1.0f / 128.0f) - mean * mean;
      float rstd = rsqrtf(var + LN_EPS);
      int n = n0 + rr;
      if (n < H_N) {
#pragma unroll
        for (int nl = 0; nl < 2; ++nl) {
          int col = cb + nl * 16 + row;
          out[(size_t)n * 128 + col] =
              (z[m][nl][r] - mean) * rstd * gamma[col] + beta[col];
        }
      }
    }
}

// ---------------------------------------------------------------------------
extern "C" void kernel_launch(void* const* d_in, const int* in_sizes, int n_in,
                              void* d_out, int out_size, void* d_ws, size_t ws_size,
                              hipStream_t stream) {
  const float* x_h   = (const float*)d_in[0];
  const float* attr  = (const float*)d_in[1];
  const float* Wp    = (const float*)d_in[2];
  const float* bp    = (const float*)d_in[3];
  const float* We1   = (const float*)d_in[4];
  const float* be1   = (const float*)d_in[5];
  const float* We2   = (const float*)d_in[6];
  const float* be2   = (const float*)d_in[7];
  const float* Wn1   = (const float*)d_in[8];
  const float* bn1   = (const float*)d_in[9];
  const float* Wn2   = (const float*)d_in[10];
  const float* bn2   = (const float*)d_in[11];
  const float* gamma = (const float*)d_in[12];
  const float* beta  = (const float*)d_in[13];
  const int*   fg    = (const int*)d_in[14];
  const int*   res   = (const int*)d_in[15];
  float* out = (float*)d_out;

  // ---- workspace layout ----
  int* bcnt_e = (int*)d_ws;                         // 8*NBUCK
  int* bcnt_h = bcnt_e + 8 * NBUCK;                 // 8*NBUCK
  unsigned* pairs_e = (unsigned*)(bcnt_h + 8 * NBUCK);  // 8*NBUCK*SUBCAP
  unsigned* pairs_h = pairs_e + (size_t)8 * NBUCK * SUBCAP;
  unsigned short* xh_bf     = (unsigned short*)(pairs_h + (size_t)8 * NBUCK * SUBCAP);
  unsigned short* edge_mean = xh_bf + (size_t)H_N * 128;
  unsigned short* edge_msg  = edge_mean + (size_t)E_N * 128;
  unsigned short* node_msg  = edge_msg + (size_t)E_N * 128;
  short* w1  = (short*)(node_msg + (size_t)H_N * 128);
  short* w2  = w1 + 128 * 192;
  short* wn1 = w2 + 128 * 128;
  short* wn2 = wn1 + 128 * 128;
  short* wp  = wn2 + 128 * 128;

  hipMemsetAsync(bcnt_e, 0, (size_t)16 * NBUCK * 4, stream);

  {
    int n4 = H_N * 128 / 4;
    k_cvt_bf16<<<(n4 + 255) / 256, 256, 0, stream>>>((const float4*)x_h, xh_bf, n4);
    n4 = 128 * 192 / 4;
    k_cvt_bf16<<<(n4 + 255) / 256, 256, 0, stream>>>((const float4*)We1, (unsigned short*)w1, n4);
    n4 = 128 * 128 / 4;
    k_cvt_bf16<<<(n4 + 255) / 256, 256, 0, stream>>>((const float4*)We2, (unsigned short*)w2, n4);
    k_cvt_bf16<<<(n4 + 255) / 256, 256, 0, stream>>>((const float4*)Wn1, (unsigned short*)wn1, n4);
    k_cvt_bf16<<<(n4 + 255) / 256, 256, 0, stream>>>((const float4*)Wn2, (unsigned short*)wn2, n4);
    k_cvt_bf16<<<(n4 + 255) / 256, 256, 0, stream>>>((const float4*)Wp, (unsigned short*)wp, n4);
  }

  k_bucket<<<(NI_N + 255) / 256, 256, 0, stream>>>(fg, res, bcnt_e, bcnt_h,
                                                   pairs_e, pairs_h);

  k_seg_mean<<<NBUCK, 256, 0, stream>>>(xh_bf, pairs_e, bcnt_e,
                                        edge_mean, E_N, SEGB_E);
  k_edge_mlp<<<E_N / 64, 256, 0, stream>>>((const short*)edge_mean, attr,
                                           w1, be1, w2, be2, edge_msg);
  k_seg_mean<<<NBUCK, 256, 0, stream>>>(edge_msg, pairs_h, bcnt_h,
                                        node_msg, H_N, SEGB_H);
  k_node_mlp_ln<<<(H_N + 63) / 64, 256, 0, stream>>>((const short*)node_msg,
                                                     (const short*)xh_bf,
                                                     wp, bp, wn1, bn1, wn2, bn2,
                                                     gamma, beta, out);
}